// Round 1
// baseline (2872.048 us; speedup 1.0000x reference)
//
#include <hip/hip_runtime.h>
#include <hip/hip_bf16.h>

// N=100000 nodes, E=1200000 edges, H=64, L=4, 2 directions.
// Pipeline: mlp -> per (dir, layer): [kqvs fused matmuls] -> [edge gather/gate/scatter] -> score.

constexpr int HDIM = 64;

// h = relu(x@W1+b1)@W2+b2, written to both h_fw and h_bw.
__global__ __launch_bounds__(256) void mlp_kernel(
    const float* __restrict__ x, const float* __restrict__ W1, const float* __restrict__ b1,
    const float* __restrict__ W2, const float* __restrict__ b2,
    float* __restrict__ hfw, float* __restrict__ hbw, int N)
{
    __shared__ float sW1[64 * 64];
    __shared__ float sW2[64 * 64];
    int t = threadIdx.x;
    for (int i = t; i < 1024; i += 256) {
        ((float4*)sW1)[i] = ((const float4*)W1)[i];
        ((float4*)sW2)[i] = ((const float4*)W2)[i];
    }
    __syncthreads();
    int lane = t & 63;
    int wid = (blockIdx.x * 256 + t) >> 6;
    int nw = (gridDim.x * 256) >> 6;
    float bb1 = b1[lane], bb2 = b2[lane];
    for (int r = wid; r < N; r += nw) {
        float xv = x[(size_t)r * 64 + lane];
        float a1 = bb1;
        #pragma unroll
        for (int f = 0; f < 64; f++)
            a1 = fmaf(__shfl(xv, f, 64), sW1[f * 64 + lane], a1);
        a1 = fmaxf(a1, 0.f);
        float a2 = bb2;
        #pragma unroll
        for (int f = 0; f < 64; f++)
            a2 = fmaf(__shfl(a1, f, 64), sW2[f * 64 + lane], a2);
        hfw[(size_t)r * 64 + lane] = a2;
        hbw[(size_t)r * 64 + lane] = a2;
    }
}

// Fused: k = h@Wk+bk, q = h@Wq+bq, v = h@Wv+bv, out = h@Ws+bs (out may alias h: each
// block stages its 32-row tile into LDS before writing, and only writes its own rows).
__global__ __launch_bounds__(256) void kqvs_kernel(
    const float* h,  // NOT restrict: aliases oo
    const float* __restrict__ Wk, const float* __restrict__ bk,
    const float* __restrict__ Wq, const float* __restrict__ bq,
    const float* __restrict__ Wv, const float* __restrict__ bv,
    const float* __restrict__ Ws, const float* __restrict__ bs,
    float* __restrict__ ko, float* __restrict__ qo, float* __restrict__ vo,
    float* oo, int N)
{
    __shared__ float sW[4][64 * 64];   // 64 KB
    __shared__ float sb[4][64];
    __shared__ float sh[64][33];       // transposed h tile, padded stride 33
    int t = threadIdx.x;
    {
        const float* Wsrc[4] = {Wk, Wq, Wv, Ws};
        #pragma unroll
        for (int m = 0; m < 4; m++)
            for (int i = t; i < 1024; i += 256)
                ((float4*)sW[m])[i] = ((const float4*)Wsrc[m])[i];
        if (t < 64) { sb[0][t] = bk[t]; sb[1][t] = bq[t]; sb[2][t] = bv[t]; sb[3][t] = bs[t]; }
    }
    int base = blockIdx.x * 32;
    for (int i = t; i < 32 * 64; i += 256) {
        int r = i >> 6, f = i & 63;
        int row = base + r;
        sh[f][r] = (row < N) ? h[(size_t)row * 64 + f] : 0.f;
    }
    __syncthreads();

    int c = t & 63, rg = t >> 6;  // rg in 0..3, 8 rows per thread
    float acc[8][4];
    #pragma unroll
    for (int r = 0; r < 8; r++) {
        acc[r][0] = sb[0][c]; acc[r][1] = sb[1][c]; acc[r][2] = sb[2][c]; acc[r][3] = sb[3][c];
    }
    #pragma unroll 4
    for (int f = 0; f < 64; f++) {
        float w0 = sW[0][f * 64 + c], w1 = sW[1][f * 64 + c];
        float w2 = sW[2][f * 64 + c], w3 = sW[3][f * 64 + c];
        #pragma unroll
        for (int r = 0; r < 8; r++) {
            float hf = sh[f][rg * 8 + r];
            acc[r][0] = fmaf(hf, w0, acc[r][0]);
            acc[r][1] = fmaf(hf, w1, acc[r][1]);
            acc[r][2] = fmaf(hf, w2, acc[r][2]);
            acc[r][3] = fmaf(hf, w3, acc[r][3]);
        }
    }
    #pragma unroll
    for (int r = 0; r < 8; r++) {
        int row = base + rg * 8 + r;
        if (row < N) {
            size_t o = (size_t)row * 64 + c;
            ko[o] = acc[r][0]; qo[o] = acc[r][1]; vo[o] = acc[r][2]; oo[o] = acc[r][3];
        }
    }
}

// One wave per edge (grid-stride): out[d] += sigmoid(k[d] + q[s]) * v[s]
__global__ __launch_bounds__(256) void edge_kernel(
    const int* __restrict__ sidx, const int* __restrict__ didx,
    const float* __restrict__ kk, const float* __restrict__ qq, const float* __restrict__ vv,
    float* __restrict__ out, int E)
{
    int lane = threadIdx.x & 63;
    int wid = (blockIdx.x * 256 + threadIdx.x) >> 6;
    int nw = (gridDim.x * 256) >> 6;
    for (int e = wid; e < E; e += nw) {
        int s = sidx[e], d = didx[e];
        float g = kk[(size_t)d * 64 + lane] + qq[(size_t)s * 64 + lane];
        float vf = vv[(size_t)s * 64 + lane];
        float eta = __builtin_amdgcn_rcpf(1.f + __expf(-g));
        atomicAdd(&out[(size_t)d * 64 + lane], eta * vf);
    }
}

// score[r] = sum_j hfw[r][j]*Wsc[j] + hbw[r][j]*Wsc[64+j] + bsc
__global__ __launch_bounds__(256) void score_kernel(
    const float* __restrict__ hfw, const float* __restrict__ hbw,
    const float* __restrict__ Wsc, const float* __restrict__ bsc,
    float* __restrict__ out, int N)
{
    int lane = threadIdx.x & 63;
    int wid = (blockIdx.x * 256 + threadIdx.x) >> 6;
    int nw = (gridDim.x * 256) >> 6;
    float wf = Wsc[lane], wb = Wsc[64 + lane], b = bsc[0];
    for (int r = wid; r < N; r += nw) {
        float p = hfw[(size_t)r * 64 + lane] * wf + hbw[(size_t)r * 64 + lane] * wb;
        #pragma unroll
        for (int off = 32; off; off >>= 1) p += __shfl_xor(p, off, 64);
        if (lane == 0) out[r] = p + b;
    }
}

extern "C" void kernel_launch(void* const* d_in, const int* in_sizes, int n_in,
                              void* d_out, int out_size, void* d_ws, size_t ws_size,
                              hipStream_t stream)
{
    const float* x   = (const float*)d_in[0];
    const int*   ei  = (const int*)d_in[1];
    const float* W1  = (const float*)d_in[2];
    const float* b1  = (const float*)d_in[3];
    const float* W2  = (const float*)d_in[4];
    const float* b2  = (const float*)d_in[5];
    const float* gWk = (const float*)d_in[6];
    const float* gbk = (const float*)d_in[7];
    const float* gWq = (const float*)d_in[8];
    const float* gbq = (const float*)d_in[9];
    const float* gWv = (const float*)d_in[10];
    const float* gbv = (const float*)d_in[11];
    const float* gWs = (const float*)d_in[12];
    const float* gb  = (const float*)d_in[13];
    const float* Wsc = (const float*)d_in[14];
    const float* bsc = (const float*)d_in[15];

    const int N = in_sizes[0] / HDIM;
    const int E = in_sizes[1] / 2;
    const int L = 4;

    // Workspace: 5 arrays of N*64 fp32 = 128 MB total.
    size_t N64 = (size_t)N * HDIM;
    float* ws   = (float*)d_ws;
    float* h_fw = ws;
    float* h_bw = ws + N64;
    float* kbuf = ws + 2 * N64;
    float* qbuf = ws + 3 * N64;
    float* vbuf = ws + 4 * N64;

    mlp_kernel<<<1024, 256, 0, stream>>>(x, W1, b1, W2, b2, h_fw, h_bw, N);

    const int* srcA = ei;        // edge_index[0]
    const int* dstA = ei + E;    // edge_index[1]
    int kb = (N + 31) / 32;

    for (int dir = 0; dir < 2; dir++) {
        float* h = dir ? h_bw : h_fw;
        // fw: eta = sig(k[dst]+q[src]), aggregate at dst.
        // bw: roles swapped (reference calls conv with (dst, src)).
        const int* sp = dir ? dstA : srcA;
        const int* dp = dir ? srcA : dstA;
        for (int l = 0; l < L; l++) {
            int off = dir * L + l;
            kqvs_kernel<<<kb, 256, 0, stream>>>(h,
                gWk + (size_t)off * 4096, gbk + (size_t)off * 64,
                gWq + (size_t)off * 4096, gbq + (size_t)off * 64,
                gWv + (size_t)off * 4096, gbv + (size_t)off * 64,
                gWs + (size_t)off * 4096, gb  + (size_t)off * 64,
                kbuf, qbuf, vbuf, h, N);
            edge_kernel<<<4096, 256, 0, stream>>>(sp, dp, kbuf, qbuf, vbuf, h, E);
        }
    }

    score_kernel<<<1024, 256, 0, stream>>>(h_fw, h_bw, Wsc, bsc, (float*)d_out, N);
}

// Round 2
// 2064.870 us; speedup vs baseline: 1.3909x; 1.3909x over previous
//
#include <hip/hip_runtime.h>
#include <hip/hip_bf16.h>
#include <hip/hip_fp16.h>

// N=100000 nodes, E=1200000 edges, H=64, L=4, 2 directions.
// Pipeline: mlp -> CSR build (both dirs) -> per (dir, layer): [kqvs fused matmuls]
//           -> [CSR edge gather/gate/segment-sum] -> score.

constexpr int HDIM = 64;

union H2U { uint32_t u; __half2 h2; };

// h = relu(x@W1+b1)@W2+b2, written to both h_fw and h_bw.
__global__ __launch_bounds__(256) void mlp_kernel(
    const float* __restrict__ x, const float* __restrict__ W1, const float* __restrict__ b1,
    const float* __restrict__ W2, const float* __restrict__ b2,
    float* __restrict__ hfw, float* __restrict__ hbw, int N)
{
    __shared__ float sW1[64 * 64];
    __shared__ float sW2[64 * 64];
    int t = threadIdx.x;
    for (int i = t; i < 1024; i += 256) {
        ((float4*)sW1)[i] = ((const float4*)W1)[i];
        ((float4*)sW2)[i] = ((const float4*)W2)[i];
    }
    __syncthreads();
    int lane = t & 63;
    int wid = (blockIdx.x * 256 + t) >> 6;
    int nw = (gridDim.x * 256) >> 6;
    float bb1 = b1[lane], bb2 = b2[lane];
    for (int r = wid; r < N; r += nw) {
        float xv = x[(size_t)r * 64 + lane];
        float a1 = bb1;
        #pragma unroll
        for (int f = 0; f < 64; f++)
            a1 = fmaf(__shfl(xv, f, 64), sW1[f * 64 + lane], a1);
        a1 = fmaxf(a1, 0.f);
        float a2 = bb2;
        #pragma unroll
        for (int f = 0; f < 64; f++)
            a2 = fmaf(__shfl(a1, f, 64), sW2[f * 64 + lane], a2);
        hfw[(size_t)r * 64 + lane] = a2;
        hbw[(size_t)r * 64 + lane] = a2;
    }
}

// ---------------- CSR build ----------------
__global__ __launch_bounds__(256) void hist_kernel(
    const int* __restrict__ srcA, const int* __restrict__ dstA,
    int* __restrict__ cnt_fw, int* __restrict__ cnt_bw, int E)
{
    int e = blockIdx.x * 256 + threadIdx.x;
    if (e < E) {
        atomicAdd(&cnt_fw[dstA[e]], 1);
        atomicAdd(&cnt_bw[srcA[e]], 1);
    }
}

// Per-block inclusive scan of 256 counts -> exclusive local, block total to bsum.
__global__ __launch_bounds__(256) void scan_local_kernel(
    const int* __restrict__ cnt, int* __restrict__ ptr, int* __restrict__ bsum, int N)
{
    __shared__ int sd[256];
    int t = threadIdx.x;
    int i = blockIdx.x * 256 + t;
    int val = (i < N) ? cnt[i] : 0;
    sd[t] = val;
    __syncthreads();
    #pragma unroll
    for (int off = 1; off < 256; off <<= 1) {
        int tmp = (t >= off) ? sd[t - off] : 0;
        __syncthreads();
        sd[t] += tmp;
        __syncthreads();
    }
    if (i < N) ptr[i] = sd[t] - val;       // exclusive, local
    if (t == 255) bsum[blockIdx.x] = sd[255];
}

__global__ __launch_bounds__(512) void scan_bsum_kernel(int* __restrict__ bsum, int nb)
{
    __shared__ int sd[512];
    int t = threadIdx.x;
    int val = (t < nb) ? bsum[t] : 0;
    sd[t] = val;
    __syncthreads();
    #pragma unroll
    for (int off = 1; off < 512; off <<= 1) {
        int tmp = (t >= off) ? sd[t - off] : 0;
        __syncthreads();
        sd[t] += tmp;
        __syncthreads();
    }
    if (t < nb) bsum[t] = sd[t] - val;     // exclusive
}

__global__ __launch_bounds__(256) void add_off_kernel(
    int* __restrict__ ptr, const int* __restrict__ bsum, int* __restrict__ cur, int N, int E)
{
    int i = blockIdx.x * 256 + threadIdx.x;
    if (i < N) {
        int p = ptr[i] + bsum[blockIdx.x];
        ptr[i] = p;
        cur[i] = p;
    }
    if (i == 0) ptr[N] = E;
}

__global__ __launch_bounds__(256) void scatter_kernel(
    const int* __restrict__ srcA, const int* __restrict__ dstA,
    int* __restrict__ cur_fw, int* __restrict__ cur_bw,
    int* __restrict__ col_fw, int* __restrict__ col_bw, int E)
{
    int e = blockIdx.x * 256 + threadIdx.x;
    if (e < E) {
        int s = srcA[e], d = dstA[e];
        col_fw[atomicAdd(&cur_fw[d], 1)] = s;   // fw: segments by dst, neighbors = src
        col_bw[atomicAdd(&cur_bw[s], 1)] = d;   // bw: segments by src, neighbors = dst
    }
}

// ---------------- fused k/q/v/s matmuls ----------------
// k = h@Wk+bk (fp32), qv = pack_half2(h@Wq+bq, h@Wv+bv), h <- h@Ws+bs (in place;
// each block stages its 32-row h tile to LDS before writing its own rows).
__global__ __launch_bounds__(256) void kqvs_kernel(
    const float* h,  // NOT restrict: aliases oo
    const float* __restrict__ Wk, const float* __restrict__ bk,
    const float* __restrict__ Wq, const float* __restrict__ bq,
    const float* __restrict__ Wv, const float* __restrict__ bv,
    const float* __restrict__ Ws, const float* __restrict__ bs,
    float* __restrict__ ko, uint32_t* __restrict__ qvo,
    float* oo, int N)
{
    __shared__ float sW[4][64 * 64];   // 64 KB
    __shared__ float sb[4][64];
    __shared__ float sh[64][36];       // transposed h tile; stride 36 floats = 144 B (16B-aligned rows)
    int t = threadIdx.x;
    {
        const float* Wsrc[4] = {Wk, Wq, Wv, Ws};
        #pragma unroll
        for (int m = 0; m < 4; m++)
            for (int i = t; i < 1024; i += 256)
                ((float4*)sW[m])[i] = ((const float4*)Wsrc[m])[i];
        if (t < 64) { sb[0][t] = bk[t]; sb[1][t] = bq[t]; sb[2][t] = bv[t]; sb[3][t] = bs[t]; }
    }
    int base = blockIdx.x * 32;
    for (int i = t; i < 32 * 64; i += 256) {
        int r = i >> 6, f = i & 63;
        int row = base + r;
        sh[f][r] = (row < N) ? h[(size_t)row * 64 + f] : 0.f;
    }
    __syncthreads();

    int c = t & 63, rg = t >> 6;  // rg in 0..3, 8 rows per thread
    float acc[8][4];
    #pragma unroll
    for (int r = 0; r < 8; r++) {
        acc[r][0] = sb[0][c]; acc[r][1] = sb[1][c]; acc[r][2] = sb[2][c]; acc[r][3] = sb[3][c];
    }
    #pragma unroll 4
    for (int f = 0; f < 64; f++) {
        float w0 = sW[0][f * 64 + c], w1 = sW[1][f * 64 + c];
        float w2 = sW[2][f * 64 + c], w3 = sW[3][f * 64 + c];
        float4 ha = *(const float4*)&sh[f][rg * 8];      // broadcast b128 reads
        float4 hb = *(const float4*)&sh[f][rg * 8 + 4];
        float hr[8] = {ha.x, ha.y, ha.z, ha.w, hb.x, hb.y, hb.z, hb.w};
        #pragma unroll
        for (int r = 0; r < 8; r++) {
            acc[r][0] = fmaf(hr[r], w0, acc[r][0]);
            acc[r][1] = fmaf(hr[r], w1, acc[r][1]);
            acc[r][2] = fmaf(hr[r], w2, acc[r][2]);
            acc[r][3] = fmaf(hr[r], w3, acc[r][3]);
        }
    }
    #pragma unroll
    for (int r = 0; r < 8; r++) {
        int row = base + rg * 8 + r;
        if (row < N) {
            size_t o = (size_t)row * 64 + c;
            ko[o] = acc[r][0];
            H2U pk;
            pk.h2.x = __float2half_rn(acc[r][1]);
            pk.h2.y = __float2half_rn(acc[r][2]);
            qvo[o] = pk.u;
            oo[o] = acc[r][3];
        }
    }
}

// ---------------- CSR edge aggregation ----------------
// Wave per node i: h[i] = (h[i] already holds h@Ws+b) + sum_j sigmoid(k[i]+q[col[j]])*v[col[j]]
__global__ __launch_bounds__(256) void edge_csr_kernel(
    const int* __restrict__ ptr, const int* __restrict__ col,
    const float* __restrict__ kk, const uint32_t* __restrict__ qv,
    float* h, int N)
{
    int lane = threadIdx.x & 63;
    int wid = (blockIdx.x * 256 + threadIdx.x) >> 6;
    int nw = (gridDim.x * 256) >> 6;
    for (int i = wid; i < N; i += nw) {
        int j = ptr[i], je = ptr[i + 1];
        float kd = kk[(size_t)i * 64 + lane];
        float acc = 0.f;
        int s0 = 0; uint32_t u0 = 0;
        if (j < je) {
            s0 = __builtin_amdgcn_readfirstlane(col[j]);
            u0 = qv[(size_t)s0 * 64 + lane];
        }
        while (j < je) {
            uint32_t u = u0;
            ++j;
            if (j < je) {   // prefetch next edge while computing current
                s0 = __builtin_amdgcn_readfirstlane(col[j]);
                u0 = qv[(size_t)s0 * 64 + lane];
            }
            H2U c; c.u = u;
            float qf = __low2float(c.h2);
            float vf = __high2float(c.h2);
            float eta = __builtin_amdgcn_rcpf(1.f + __expf(-(kd + qf)));
            acc = fmaf(eta, vf, acc);
        }
        size_t o = (size_t)i * 64 + lane;
        h[o] = acc + h[o];
    }
}

// score[r] = sum_j hfw[r][j]*Wsc[j] + hbw[r][j]*Wsc[64+j] + bsc
__global__ __launch_bounds__(256) void score_kernel(
    const float* __restrict__ hfw, const float* __restrict__ hbw,
    const float* __restrict__ Wsc, const float* __restrict__ bsc,
    float* __restrict__ out, int N)
{
    int lane = threadIdx.x & 63;
    int wid = (blockIdx.x * 256 + threadIdx.x) >> 6;
    int nw = (gridDim.x * 256) >> 6;
    float wf = Wsc[lane], wb = Wsc[64 + lane], b = bsc[0];
    for (int r = wid; r < N; r += nw) {
        float p = hfw[(size_t)r * 64 + lane] * wf + hbw[(size_t)r * 64 + lane] * wb;
        #pragma unroll
        for (int off = 32; off; off >>= 1) p += __shfl_xor(p, off, 64);
        if (lane == 0) out[r] = p + b;
    }
}

extern "C" void kernel_launch(void* const* d_in, const int* in_sizes, int n_in,
                              void* d_out, int out_size, void* d_ws, size_t ws_size,
                              hipStream_t stream)
{
    const float* x   = (const float*)d_in[0];
    const int*   ei  = (const int*)d_in[1];
    const float* W1  = (const float*)d_in[2];
    const float* b1  = (const float*)d_in[3];
    const float* W2  = (const float*)d_in[4];
    const float* b2  = (const float*)d_in[5];
    const float* gWk = (const float*)d_in[6];
    const float* gbk = (const float*)d_in[7];
    const float* gWq = (const float*)d_in[8];
    const float* gbq = (const float*)d_in[9];
    const float* gWv = (const float*)d_in[10];
    const float* gbv = (const float*)d_in[11];
    const float* gWs = (const float*)d_in[12];
    const float* gb  = (const float*)d_in[13];
    const float* Wsc = (const float*)d_in[14];
    const float* bsc = (const float*)d_in[15];

    const int N = in_sizes[0] / HDIM;
    const int E = in_sizes[1] / 2;
    const int L = 4;

    // ---- workspace layout (floats) ----
    size_t N64 = (size_t)N * HDIM;
    size_t Npad = (size_t)N + 64;
    float* ws    = (float*)d_ws;
    float* h_fw  = ws;
    float* h_bw  = ws + N64;
    float* kbuf  = ws + 2 * N64;
    uint32_t* qvbuf = (uint32_t*)(ws + 3 * N64);
    int* ptr_fw  = (int*)(ws + 4 * N64);
    int* ptr_bw  = ptr_fw + Npad;
    int* cnt_fw  = ptr_bw + Npad;    // reused as scatter cursor
    int* cnt_bw  = cnt_fw + Npad;
    int* col_fw  = cnt_bw + Npad;
    int* col_bw  = col_fw + E;
    int* bs_fw   = col_bw + E;
    int* bs_bw   = bs_fw + 512;

    const int* srcA = ei;        // edge_index[0]
    const int* dstA = ei + E;    // edge_index[1]

    int nb  = (N + 255) / 256;
    int neb = (E + 255) / 256;

    // ---- MLP (independent of CSR build) ----
    mlp_kernel<<<1024, 256, 0, stream>>>(x, W1, b1, W2, b2, h_fw, h_bw, N);

    // ---- CSR build for both directions ----
    hipMemsetAsync(cnt_fw, 0, 2 * Npad * sizeof(int), stream);
    hist_kernel<<<neb, 256, 0, stream>>>(srcA, dstA, cnt_fw, cnt_bw, E);
    scan_local_kernel<<<nb, 256, 0, stream>>>(cnt_fw, ptr_fw, bs_fw, N);
    scan_local_kernel<<<nb, 256, 0, stream>>>(cnt_bw, ptr_bw, bs_bw, N);
    scan_bsum_kernel<<<1, 512, 0, stream>>>(bs_fw, nb);
    scan_bsum_kernel<<<1, 512, 0, stream>>>(bs_bw, nb);
    add_off_kernel<<<nb, 256, 0, stream>>>(ptr_fw, bs_fw, cnt_fw, N, E);
    add_off_kernel<<<nb, 256, 0, stream>>>(ptr_bw, bs_bw, cnt_bw, N, E);
    scatter_kernel<<<neb, 256, 0, stream>>>(srcA, dstA, cnt_fw, cnt_bw, col_fw, col_bw, E);

    int kb = (N + 31) / 32;
    for (int dir = 0; dir < 2; dir++) {
        float* h = dir ? h_bw : h_fw;
        const int* ptr = dir ? ptr_bw : ptr_fw;
        const int* col = dir ? col_bw : col_fw;
        for (int l = 0; l < L; l++) {
            int off = dir * L + l;
            kqvs_kernel<<<kb, 256, 0, stream>>>(h,
                gWk + (size_t)off * 4096, gbk + (size_t)off * 64,
                gWq + (size_t)off * 4096, gbq + (size_t)off * 64,
                gWv + (size_t)off * 4096, gbv + (size_t)off * 64,
                gWs + (size_t)off * 4096, gb  + (size_t)off * 64,
                kbuf, qvbuf, h, N);
            edge_csr_kernel<<<2048, 256, 0, stream>>>(ptr, col, kbuf, qvbuf, h, N);
        }
    }

    score_kernel<<<1024, 256, 0, stream>>>(h_fw, h_bw, Wsc, bsc, (float*)d_out, N);
}

// Round 3
// 1460.215 us; speedup vs baseline: 1.9669x; 1.4141x over previous
//
#include <hip/hip_runtime.h>
#include <hip/hip_bf16.h>
#include <hip/hip_fp16.h>

// N=100000 nodes, E=1200000 edges, H=64, L=4, 2 directions.
// Pipeline: mlp -> CSR build (both dirs) -> per (dir, layer): [kqvs fused matmuls]
//           -> [CSR edge gather/gate/segment-sum, 4-deep pipelined] -> score.

constexpr int HDIM = 64;

union H2U { uint32_t u; __half2 h2; };
union H1U { unsigned short u; __half h; };

// h = relu(x@W1+b1)@W2+b2, written to both h_fw and h_bw.
__global__ __launch_bounds__(256) void mlp_kernel(
    const float* __restrict__ x, const float* __restrict__ W1, const float* __restrict__ b1,
    const float* __restrict__ W2, const float* __restrict__ b2,
    float* __restrict__ hfw, float* __restrict__ hbw, int N)
{
    __shared__ float sW1[64 * 64];
    __shared__ float sW2[64 * 64];
    int t = threadIdx.x;
    for (int i = t; i < 1024; i += 256) {
        ((float4*)sW1)[i] = ((const float4*)W1)[i];
        ((float4*)sW2)[i] = ((const float4*)W2)[i];
    }
    __syncthreads();
    int lane = t & 63;
    int wid = (blockIdx.x * 256 + t) >> 6;
    int nw = (gridDim.x * 256) >> 6;
    float bb1 = b1[lane], bb2 = b2[lane];
    for (int r = wid; r < N; r += nw) {
        float xv = x[(size_t)r * 64 + lane];
        float a1 = bb1;
        #pragma unroll
        for (int f = 0; f < 64; f++)
            a1 = fmaf(__shfl(xv, f, 64), sW1[f * 64 + lane], a1);
        a1 = fmaxf(a1, 0.f);
        float a2 = bb2;
        #pragma unroll
        for (int f = 0; f < 64; f++)
            a2 = fmaf(__shfl(a1, f, 64), sW2[f * 64 + lane], a2);
        hfw[(size_t)r * 64 + lane] = a2;
        hbw[(size_t)r * 64 + lane] = a2;
    }
}

// ---------------- CSR build ----------------
__global__ __launch_bounds__(256) void hist_kernel(
    const int* __restrict__ srcA, const int* __restrict__ dstA,
    int* __restrict__ cnt_fw, int* __restrict__ cnt_bw, int E)
{
    int e = blockIdx.x * 256 + threadIdx.x;
    if (e < E) {
        atomicAdd(&cnt_fw[dstA[e]], 1);
        atomicAdd(&cnt_bw[srcA[e]], 1);
    }
}

// Per-block inclusive scan of 256 counts -> exclusive local, block total to bsum.
// grid.y = direction (0: fw arrays, 1: bw arrays).
__global__ __launch_bounds__(256) void scan_local_kernel(
    const int* __restrict__ c0, int* __restrict__ p0, int* __restrict__ b0,
    const int* __restrict__ c1, int* __restrict__ p1, int* __restrict__ b1, int N)
{
    const int* cnt = blockIdx.y ? c1 : c0;
    int* ptr  = blockIdx.y ? p1 : p0;
    int* bsum = blockIdx.y ? b1 : b0;
    __shared__ int sd[256];
    int t = threadIdx.x;
    int i = blockIdx.x * 256 + t;
    int val = (i < N) ? cnt[i] : 0;
    sd[t] = val;
    __syncthreads();
    #pragma unroll
    for (int off = 1; off < 256; off <<= 1) {
        int tmp = (t >= off) ? sd[t - off] : 0;
        __syncthreads();
        sd[t] += tmp;
        __syncthreads();
    }
    if (i < N) ptr[i] = sd[t] - val;       // exclusive, local
    if (t == 255) bsum[blockIdx.x] = sd[255];
}

// One block per direction (blockIdx.x in {0,1}).
__global__ __launch_bounds__(512) void scan_bsum_kernel(
    int* __restrict__ b0, int* __restrict__ b1, int nb)
{
    int* bsum = blockIdx.x ? b1 : b0;
    __shared__ int sd[512];
    int t = threadIdx.x;
    int val = (t < nb) ? bsum[t] : 0;
    sd[t] = val;
    __syncthreads();
    #pragma unroll
    for (int off = 1; off < 512; off <<= 1) {
        int tmp = (t >= off) ? sd[t - off] : 0;
        __syncthreads();
        sd[t] += tmp;
        __syncthreads();
    }
    if (t < nb) bsum[t] = sd[t] - val;     // exclusive
}

// grid.y = direction.
__global__ __launch_bounds__(256) void add_off_kernel(
    int* __restrict__ p0, const int* __restrict__ b0, int* __restrict__ u0,
    int* __restrict__ p1, const int* __restrict__ b1, int* __restrict__ u1, int N, int E)
{
    int* ptr = blockIdx.y ? p1 : p0;
    const int* bsum = blockIdx.y ? b1 : b0;
    int* cur = blockIdx.y ? u1 : u0;
    int i = blockIdx.x * 256 + threadIdx.x;
    if (i < N) {
        int p = ptr[i] + bsum[blockIdx.x];
        ptr[i] = p;
        cur[i] = p;
    }
    if (i == 0) ptr[N] = E;
}

__global__ __launch_bounds__(256) void scatter_kernel(
    const int* __restrict__ srcA, const int* __restrict__ dstA,
    int* __restrict__ cur_fw, int* __restrict__ cur_bw,
    int* __restrict__ col_fw, int* __restrict__ col_bw, int E)
{
    int e = blockIdx.x * 256 + threadIdx.x;
    if (e < E) {
        int s = srcA[e], d = dstA[e];
        col_fw[atomicAdd(&cur_fw[d], 1)] = s;   // fw: segments by dst, neighbors = src
        col_bw[atomicAdd(&cur_bw[s], 1)] = d;   // bw: segments by src, neighbors = dst
    }
}

// ---------------- fused k/q/v/s matmuls ----------------
// k = fp16(h@Wk+bk), qv = pack_half2(h@Wq+bq, h@Wv+bv), h <- h@Ws+bs (in place;
// each block stages its 32-row h tile to LDS before writing its own rows).
__global__ __launch_bounds__(256) void kqvs_kernel(
    const float* h,  // NOT restrict: aliases oo
    const float* __restrict__ Wk, const float* __restrict__ bk,
    const float* __restrict__ Wq, const float* __restrict__ bq,
    const float* __restrict__ Wv, const float* __restrict__ bv,
    const float* __restrict__ Ws, const float* __restrict__ bs,
    unsigned short* __restrict__ ko, uint32_t* __restrict__ qvo,
    float* oo, int N)
{
    __shared__ float sW[4][64 * 64];   // 64 KB
    __shared__ float sb[4][64];
    __shared__ float sh[64][36];       // transposed h tile; stride 36 floats (16B-aligned rows)
    int t = threadIdx.x;
    {
        const float* Wsrc[4] = {Wk, Wq, Wv, Ws};
        #pragma unroll
        for (int m = 0; m < 4; m++)
            for (int i = t; i < 1024; i += 256)
                ((float4*)sW[m])[i] = ((const float4*)Wsrc[m])[i];
        if (t < 64) { sb[0][t] = bk[t]; sb[1][t] = bq[t]; sb[2][t] = bv[t]; sb[3][t] = bs[t]; }
    }
    int base = blockIdx.x * 32;
    for (int i = t; i < 32 * 16; i += 256) {   // 512 float4 loads, 2 iters/thread
        int r = i >> 4, fq = i & 15;
        int row = base + r;
        float4 hv = make_float4(0.f, 0.f, 0.f, 0.f);
        if (row < N) hv = ((const float4*)h)[(size_t)row * 16 + fq];
        sh[fq * 4 + 0][r] = hv.x; sh[fq * 4 + 1][r] = hv.y;
        sh[fq * 4 + 2][r] = hv.z; sh[fq * 4 + 3][r] = hv.w;
    }
    __syncthreads();

    int c = t & 63, rg = t >> 6;  // rg in 0..3, 8 rows per thread
    float acc[8][4];
    #pragma unroll
    for (int r = 0; r < 8; r++) {
        acc[r][0] = sb[0][c]; acc[r][1] = sb[1][c]; acc[r][2] = sb[2][c]; acc[r][3] = sb[3][c];
    }
    #pragma unroll 4
    for (int f = 0; f < 64; f++) {
        float w0 = sW[0][f * 64 + c], w1 = sW[1][f * 64 + c];
        float w2 = sW[2][f * 64 + c], w3 = sW[3][f * 64 + c];
        float4 ha = *(const float4*)&sh[f][rg * 8];      // broadcast b128 reads
        float4 hb = *(const float4*)&sh[f][rg * 8 + 4];
        float hr[8] = {ha.x, ha.y, ha.z, ha.w, hb.x, hb.y, hb.z, hb.w};
        #pragma unroll
        for (int r = 0; r < 8; r++) {
            acc[r][0] = fmaf(hr[r], w0, acc[r][0]);
            acc[r][1] = fmaf(hr[r], w1, acc[r][1]);
            acc[r][2] = fmaf(hr[r], w2, acc[r][2]);
            acc[r][3] = fmaf(hr[r], w3, acc[r][3]);
        }
    }
    #pragma unroll
    for (int r = 0; r < 8; r++) {
        int row = base + rg * 8 + r;
        if (row < N) {
            size_t o = (size_t)row * 64 + c;
            H1U pk1; pk1.h = __float2half_rn(acc[r][0]);
            ko[o] = pk1.u;
            H2U pk;
            pk.h2.x = __float2half_rn(acc[r][1]);
            pk.h2.y = __float2half_rn(acc[r][2]);
            qvo[o] = pk.u;
            oo[o] = acc[r][3];
        }
    }
}

// ---------------- CSR edge aggregation ----------------
__device__ __forceinline__ float gate_term(float kd, uint32_t u) {
    H2U c; c.u = u;
    float qf = __low2float(c.h2);
    float vf = __high2float(c.h2);
    float eta = __builtin_amdgcn_rcpf(1.f + __expf(-(kd + qf)));
    return eta * vf;
}

// Wave per node i: h[i] = (h[i] already holds h@Ws+b) + sum_j sigmoid(k[i]+q[col[j]])*v[col[j]]
// 4-deep gather pipeline: 4 independent qv gathers in flight per wave.
__global__ __launch_bounds__(256) void edge_csr_kernel(
    const int* __restrict__ ptr, const int* __restrict__ col,
    const unsigned short* __restrict__ kh, const uint32_t* __restrict__ qv,
    float* h, int N)
{
    int lane = threadIdx.x & 63;
    int wid = (blockIdx.x * 256 + threadIdx.x) >> 6;
    int nw = (gridDim.x * 256) >> 6;
    for (int i = wid; i < N; i += nw) {
        int j = ptr[i], je = ptr[i + 1];
        H1U ku; ku.u = kh[(size_t)i * 64 + lane];
        float kd = __half2float(ku.h);
        float acc = 0.f;
        while (j + 4 <= je) {
            int s0 = __builtin_amdgcn_readfirstlane(col[j + 0]);
            int s1 = __builtin_amdgcn_readfirstlane(col[j + 1]);
            int s2 = __builtin_amdgcn_readfirstlane(col[j + 2]);
            int s3 = __builtin_amdgcn_readfirstlane(col[j + 3]);
            uint32_t u0 = qv[(size_t)s0 * 64 + lane];
            uint32_t u1 = qv[(size_t)s1 * 64 + lane];
            uint32_t u2 = qv[(size_t)s2 * 64 + lane];
            uint32_t u3 = qv[(size_t)s3 * 64 + lane];
            acc += gate_term(kd, u0);
            acc += gate_term(kd, u1);
            acc += gate_term(kd, u2);
            acc += gate_term(kd, u3);
            j += 4;
        }
        while (j < je) {
            int s0 = __builtin_amdgcn_readfirstlane(col[j]);
            uint32_t u0 = qv[(size_t)s0 * 64 + lane];
            acc += gate_term(kd, u0);
            ++j;
        }
        size_t o = (size_t)i * 64 + lane;
        h[o] = acc + h[o];
    }
}

// score[r] = sum_j hfw[r][j]*Wsc[j] + hbw[r][j]*Wsc[64+j] + bsc
__global__ __launch_bounds__(256) void score_kernel(
    const float* __restrict__ hfw, const float* __restrict__ hbw,
    const float* __restrict__ Wsc, const float* __restrict__ bsc,
    float* __restrict__ out, int N)
{
    int lane = threadIdx.x & 63;
    int wid = (blockIdx.x * 256 + threadIdx.x) >> 6;
    int nw = (gridDim.x * 256) >> 6;
    float wf = Wsc[lane], wb = Wsc[64 + lane], b = bsc[0];
    for (int r = wid; r < N; r += nw) {
        float p = hfw[(size_t)r * 64 + lane] * wf + hbw[(size_t)r * 64 + lane] * wb;
        #pragma unroll
        for (int off = 32; off; off >>= 1) p += __shfl_xor(p, off, 64);
        if (lane == 0) out[r] = p + b;
    }
}

extern "C" void kernel_launch(void* const* d_in, const int* in_sizes, int n_in,
                              void* d_out, int out_size, void* d_ws, size_t ws_size,
                              hipStream_t stream)
{
    const float* x   = (const float*)d_in[0];
    const int*   ei  = (const int*)d_in[1];
    const float* W1  = (const float*)d_in[2];
    const float* b1  = (const float*)d_in[3];
    const float* W2  = (const float*)d_in[4];
    const float* b2  = (const float*)d_in[5];
    const float* gWk = (const float*)d_in[6];
    const float* gbk = (const float*)d_in[7];
    const float* gWq = (const float*)d_in[8];
    const float* gbq = (const float*)d_in[9];
    const float* gWv = (const float*)d_in[10];
    const float* gbv = (const float*)d_in[11];
    const float* gWs = (const float*)d_in[12];
    const float* gb  = (const float*)d_in[13];
    const float* Wsc = (const float*)d_in[14];
    const float* bsc = (const float*)d_in[15];

    const int N = in_sizes[0] / HDIM;
    const int E = in_sizes[1] / 2;
    const int L = 4;

    // ---- workspace layout (floats) ----
    size_t N64 = (size_t)N * HDIM;
    size_t Npad = (size_t)N + 64;
    float* ws    = (float*)d_ws;
    float* h_fw  = ws;
    float* h_bw  = ws + N64;
    unsigned short* kbuf = (unsigned short*)(ws + 2 * N64);   // N64 ushorts (fits in N64 floats)
    uint32_t* qvbuf = (uint32_t*)(ws + 3 * N64);
    int* ptr_fw  = (int*)(ws + 4 * N64);
    int* ptr_bw  = ptr_fw + Npad;
    int* cnt_fw  = ptr_bw + Npad;    // reused as scatter cursor
    int* cnt_bw  = cnt_fw + Npad;
    int* col_fw  = cnt_bw + Npad;
    int* col_bw  = col_fw + E;
    int* bs_fw   = col_bw + E;
    int* bs_bw   = bs_fw + 512;

    const int* srcA = ei;        // edge_index[0]
    const int* dstA = ei + E;    // edge_index[1]

    int nb  = (N + 255) / 256;
    int neb = (E + 255) / 256;

    // ---- MLP (independent of CSR build) ----
    mlp_kernel<<<1024, 256, 0, stream>>>(x, W1, b1, W2, b2, h_fw, h_bw, N);

    // ---- CSR build for both directions ----
    hipMemsetAsync(cnt_fw, 0, 2 * Npad * sizeof(int), stream);
    hist_kernel<<<neb, 256, 0, stream>>>(srcA, dstA, cnt_fw, cnt_bw, E);
    scan_local_kernel<<<dim3(nb, 2), 256, 0, stream>>>(cnt_fw, ptr_fw, bs_fw,
                                                       cnt_bw, ptr_bw, bs_bw, N);
    scan_bsum_kernel<<<2, 512, 0, stream>>>(bs_fw, bs_bw, nb);
    add_off_kernel<<<dim3(nb, 2), 256, 0, stream>>>(ptr_fw, bs_fw, cnt_fw,
                                                    ptr_bw, bs_bw, cnt_bw, N, E);
    scatter_kernel<<<neb, 256, 0, stream>>>(srcA, dstA, cnt_fw, cnt_bw, col_fw, col_bw, E);

    int kb = (N + 31) / 32;
    for (int dir = 0; dir < 2; dir++) {
        float* h = dir ? h_bw : h_fw;
        const int* ptr = dir ? ptr_bw : ptr_fw;
        const int* col = dir ? col_bw : col_fw;
        for (int l = 0; l < L; l++) {
            int off = dir * L + l;
            kqvs_kernel<<<kb, 256, 0, stream>>>(h,
                gWk + (size_t)off * 4096, gbk + (size_t)off * 64,
                gWq + (size_t)off * 4096, gbq + (size_t)off * 64,
                gWv + (size_t)off * 4096, gbv + (size_t)off * 64,
                gWs + (size_t)off * 4096, gb  + (size_t)off * 64,
                kbuf, qvbuf, h, N);
            edge_csr_kernel<<<2048, 256, 0, stream>>>(ptr, col, kbuf, qvbuf, h, N);
        }
    }

    score_kernel<<<1024, 256, 0, stream>>>(h_fw, h_bw, Wsc, bsc, (float*)d_out, N);
}

// Round 4
// 1321.002 us; speedup vs baseline: 2.1741x; 1.1054x over previous
//
#include <hip/hip_runtime.h>
#include <hip/hip_bf16.h>
#include <hip/hip_fp16.h>

// N=100000 nodes, E=1200000 edges, H=64, L=4, 2 directions.
// Pipeline: mlp -> CSR build (both dirs) -> per (dir, layer): [kqvs fused matmuls]
//           -> [CSR edge gather/gate/segment-sum, 8-deep pipelined] -> score.

constexpr int HDIM = 64;

union H2U { uint32_t u; __half2 h2; };
union H1U { unsigned short u; __half h; };

// h = relu(x@W1+b1)@W2+b2, written to both h_fw and h_bw.
__global__ __launch_bounds__(256) void mlp_kernel(
    const float* __restrict__ x, const float* __restrict__ W1, const float* __restrict__ b1,
    const float* __restrict__ W2, const float* __restrict__ b2,
    float* __restrict__ hfw, float* __restrict__ hbw, int N)
{
    __shared__ float sW1[64 * 64];
    __shared__ float sW2[64 * 64];
    int t = threadIdx.x;
    for (int i = t; i < 1024; i += 256) {
        ((float4*)sW1)[i] = ((const float4*)W1)[i];
        ((float4*)sW2)[i] = ((const float4*)W2)[i];
    }
    __syncthreads();
    int lane = t & 63;
    int wid = (blockIdx.x * 256 + t) >> 6;
    int nw = (gridDim.x * 256) >> 6;
    float bb1 = b1[lane], bb2 = b2[lane];
    for (int r = wid; r < N; r += nw) {
        float xv = x[(size_t)r * 64 + lane];
        float a1 = bb1;
        #pragma unroll
        for (int f = 0; f < 64; f++)
            a1 = fmaf(__shfl(xv, f, 64), sW1[f * 64 + lane], a1);
        a1 = fmaxf(a1, 0.f);
        float a2 = bb2;
        #pragma unroll
        for (int f = 0; f < 64; f++)
            a2 = fmaf(__shfl(a1, f, 64), sW2[f * 64 + lane], a2);
        hfw[(size_t)r * 64 + lane] = a2;
        hbw[(size_t)r * 64 + lane] = a2;
    }
}

// ---------------- CSR build ----------------
// 4 edges per thread: atomics are fire-and-forget here, but batching still cuts
// instruction/launch overhead.
__global__ __launch_bounds__(256) void hist_kernel(
    const int* __restrict__ srcA, const int* __restrict__ dstA,
    int* __restrict__ cnt_fw, int* __restrict__ cnt_bw, int E)
{
    int tid = blockIdx.x * 256 + threadIdx.x;
    int S = gridDim.x * 256;
    #pragma unroll
    for (int k = 0; k < 4; k++) {
        int e = tid + k * S;
        if (e < E) {
            atomicAdd(&cnt_fw[dstA[e]], 1);
            atomicAdd(&cnt_bw[srcA[e]], 1);
        }
    }
}

// Per-block inclusive scan of 256 counts -> exclusive local, block total to bsum.
// grid.y = direction (0: fw arrays, 1: bw arrays).
__global__ __launch_bounds__(256) void scan_local_kernel(
    const int* __restrict__ c0, int* __restrict__ p0, int* __restrict__ b0,
    const int* __restrict__ c1, int* __restrict__ p1, int* __restrict__ b1, int N)
{
    const int* cnt = blockIdx.y ? c1 : c0;
    int* ptr  = blockIdx.y ? p1 : p0;
    int* bsum = blockIdx.y ? b1 : b0;
    __shared__ int sd[256];
    int t = threadIdx.x;
    int i = blockIdx.x * 256 + t;
    int val = (i < N) ? cnt[i] : 0;
    sd[t] = val;
    __syncthreads();
    #pragma unroll
    for (int off = 1; off < 256; off <<= 1) {
        int tmp = (t >= off) ? sd[t - off] : 0;
        __syncthreads();
        sd[t] += tmp;
        __syncthreads();
    }
    if (i < N) ptr[i] = sd[t] - val;       // exclusive, local
    if (t == 255) bsum[blockIdx.x] = sd[255];
}

// One block per direction (blockIdx.x in {0,1}).
__global__ __launch_bounds__(512) void scan_bsum_kernel(
    int* __restrict__ b0, int* __restrict__ b1, int nb)
{
    int* bsum = blockIdx.x ? b1 : b0;
    __shared__ int sd[512];
    int t = threadIdx.x;
    int val = (t < nb) ? bsum[t] : 0;
    sd[t] = val;
    __syncthreads();
    #pragma unroll
    for (int off = 1; off < 512; off <<= 1) {
        int tmp = (t >= off) ? sd[t - off] : 0;
        __syncthreads();
        sd[t] += tmp;
        __syncthreads();
    }
    if (t < nb) bsum[t] = sd[t] - val;     // exclusive
}

// grid.y = direction.
__global__ __launch_bounds__(256) void add_off_kernel(
    int* __restrict__ p0, const int* __restrict__ b0, int* __restrict__ u0,
    int* __restrict__ p1, const int* __restrict__ b1, int* __restrict__ u1, int N, int E)
{
    int* ptr = blockIdx.y ? p1 : p0;
    const int* bsum = blockIdx.y ? b1 : b0;
    int* cur = blockIdx.y ? u1 : u0;
    int i = blockIdx.x * 256 + threadIdx.x;
    if (i < N) {
        int p = ptr[i] + bsum[blockIdx.x];
        ptr[i] = p;
        cur[i] = p;
    }
    if (i == 0) ptr[N] = E;
}

// 4 edges per thread; all 8 returning atomics issued before any col write so
// the atomic round-trips overlap (this kernel was latency-bound at 1 edge/thread).
__global__ __launch_bounds__(256) void scatter_kernel(
    const int* __restrict__ srcA, const int* __restrict__ dstA,
    int* __restrict__ cur_fw, int* __restrict__ cur_bw,
    int* __restrict__ col_fw, int* __restrict__ col_bw, int E)
{
    int tid = blockIdx.x * 256 + threadIdx.x;
    int S = gridDim.x * 256;
    int s[4], d[4], pf[4], pb[4];
    bool va[4];
    #pragma unroll
    for (int k = 0; k < 4; k++) {
        int e = tid + k * S;
        va[k] = e < E;
        s[k] = va[k] ? srcA[e] : 0;
        d[k] = va[k] ? dstA[e] : 0;
    }
    #pragma unroll
    for (int k = 0; k < 4; k++) if (va[k]) pf[k] = atomicAdd(&cur_fw[d[k]], 1);
    #pragma unroll
    for (int k = 0; k < 4; k++) if (va[k]) pb[k] = atomicAdd(&cur_bw[s[k]], 1);
    #pragma unroll
    for (int k = 0; k < 4; k++) if (va[k]) { col_fw[pf[k]] = s[k]; col_bw[pb[k]] = d[k]; }
}

// ---------------- fused k/q/v/s matmuls ----------------
// Persistent blocks (512 = 2/CU): weights staged in LDS once per block, then
// grid-stride over 32-row tiles. k = fp16(h@Wk+bk), qv = pack_half2(q, v),
// h <- h@Ws+bs in place (tile staged to LDS before its rows are overwritten).
__global__ __launch_bounds__(256) void kqvs_kernel(
    const float* h,  // NOT restrict: aliases oo
    const float* __restrict__ Wk, const float* __restrict__ bk,
    const float* __restrict__ Wq, const float* __restrict__ bq,
    const float* __restrict__ Wv, const float* __restrict__ bv,
    const float* __restrict__ Ws, const float* __restrict__ bs,
    unsigned short* __restrict__ ko, uint32_t* __restrict__ qvo,
    float* oo, int N, int ntiles)
{
    __shared__ float sW[4][64 * 64];   // 64 KB
    __shared__ float sb[4][64];
    __shared__ float sh[64][36];       // transposed h tile; stride 36 floats
    int t = threadIdx.x;
    {
        const float* Wsrc[4] = {Wk, Wq, Wv, Ws};
        #pragma unroll
        for (int m = 0; m < 4; m++)
            for (int i = t; i < 1024; i += 256)
                ((float4*)sW[m])[i] = ((const float4*)Wsrc[m])[i];
        if (t < 64) { sb[0][t] = bk[t]; sb[1][t] = bq[t]; sb[2][t] = bv[t]; sb[3][t] = bs[t]; }
    }
    int c = t & 63, rg = t >> 6;  // rg in 0..3, 8 rows per thread

    for (int tile = blockIdx.x; tile < ntiles; tile += gridDim.x) {
        int base = tile * 32;
        __syncthreads();   // sh safe to overwrite (and weights visible on iter 0)
        for (int i = t; i < 32 * 16; i += 256) {   // 512 float4 loads
            int r = i >> 4, fq = i & 15;
            int row = base + r;
            float4 hv = make_float4(0.f, 0.f, 0.f, 0.f);
            if (row < N) hv = ((const float4*)h)[(size_t)row * 16 + fq];
            sh[fq * 4 + 0][r] = hv.x; sh[fq * 4 + 1][r] = hv.y;
            sh[fq * 4 + 2][r] = hv.z; sh[fq * 4 + 3][r] = hv.w;
        }
        __syncthreads();

        float acc[8][4];
        #pragma unroll
        for (int r = 0; r < 8; r++) {
            acc[r][0] = sb[0][c]; acc[r][1] = sb[1][c]; acc[r][2] = sb[2][c]; acc[r][3] = sb[3][c];
        }
        #pragma unroll 4
        for (int f = 0; f < 64; f++) {
            float w0 = sW[0][f * 64 + c], w1 = sW[1][f * 64 + c];
            float w2 = sW[2][f * 64 + c], w3 = sW[3][f * 64 + c];
            float4 ha = *(const float4*)&sh[f][rg * 8];      // broadcast b128 reads
            float4 hb = *(const float4*)&sh[f][rg * 8 + 4];
            float hr[8] = {ha.x, ha.y, ha.z, ha.w, hb.x, hb.y, hb.z, hb.w};
            #pragma unroll
            for (int r = 0; r < 8; r++) {
                acc[r][0] = fmaf(hr[r], w0, acc[r][0]);
                acc[r][1] = fmaf(hr[r], w1, acc[r][1]);
                acc[r][2] = fmaf(hr[r], w2, acc[r][2]);
                acc[r][3] = fmaf(hr[r], w3, acc[r][3]);
            }
        }
        #pragma unroll
        for (int r = 0; r < 8; r++) {
            int row = base + rg * 8 + r;
            if (row < N) {
                size_t o = (size_t)row * 64 + c;
                H1U pk1; pk1.h = __float2half_rn(acc[r][0]);
                ko[o] = pk1.u;
                H2U pk;
                pk.h2.x = __float2half_rn(acc[r][1]);
                pk.h2.y = __float2half_rn(acc[r][2]);
                qvo[o] = pk.u;
                oo[o] = acc[r][3];
            }
        }
    }
}

// ---------------- CSR edge aggregation ----------------
__device__ __forceinline__ float gate_term(float kd, uint32_t u) {
    H2U c; c.u = u;
    float qf = __low2float(c.h2);
    float vf = __high2float(c.h2);
    float eta = __builtin_amdgcn_rcpf(1.f + __expf(-(kd + qf)));
    return eta * vf;
}

// Wave per node i: h[i] = (h[i] already holds h@Ws+b) + sum_j sigmoid(k[i]+q[col[j]])*v[col[j]]
// 8-deep gather pipeline: 8 independent qv gathers in flight per wave.
__global__ __launch_bounds__(256) void edge_csr_kernel(
    const int* __restrict__ ptr, const int* __restrict__ col,
    const unsigned short* __restrict__ kh, const uint32_t* __restrict__ qv,
    float* h, int N)
{
    int lane = threadIdx.x & 63;
    int wid = (blockIdx.x * 256 + threadIdx.x) >> 6;
    int nw = (gridDim.x * 256) >> 6;
    for (int i = wid; i < N; i += nw) {
        int j = ptr[i], je = ptr[i + 1];
        size_t o = (size_t)i * 64 + lane;
        H1U ku; ku.u = kh[o];
        float hold = h[o];             // hoisted: overlaps with the gather loop
        float kd = __half2float(ku.h);
        float acc = 0.f;
        while (j + 8 <= je) {
            int s0 = __builtin_amdgcn_readfirstlane(col[j + 0]);
            int s1 = __builtin_amdgcn_readfirstlane(col[j + 1]);
            int s2 = __builtin_amdgcn_readfirstlane(col[j + 2]);
            int s3 = __builtin_amdgcn_readfirstlane(col[j + 3]);
            int s4 = __builtin_amdgcn_readfirstlane(col[j + 4]);
            int s5 = __builtin_amdgcn_readfirstlane(col[j + 5]);
            int s6 = __builtin_amdgcn_readfirstlane(col[j + 6]);
            int s7 = __builtin_amdgcn_readfirstlane(col[j + 7]);
            uint32_t u0 = qv[(size_t)s0 * 64 + lane];
            uint32_t u1 = qv[(size_t)s1 * 64 + lane];
            uint32_t u2 = qv[(size_t)s2 * 64 + lane];
            uint32_t u3 = qv[(size_t)s3 * 64 + lane];
            uint32_t u4 = qv[(size_t)s4 * 64 + lane];
            uint32_t u5 = qv[(size_t)s5 * 64 + lane];
            uint32_t u6 = qv[(size_t)s6 * 64 + lane];
            uint32_t u7 = qv[(size_t)s7 * 64 + lane];
            acc += gate_term(kd, u0);
            acc += gate_term(kd, u1);
            acc += gate_term(kd, u2);
            acc += gate_term(kd, u3);
            acc += gate_term(kd, u4);
            acc += gate_term(kd, u5);
            acc += gate_term(kd, u6);
            acc += gate_term(kd, u7);
            j += 8;
        }
        if (j + 4 <= je) {
            int s0 = __builtin_amdgcn_readfirstlane(col[j + 0]);
            int s1 = __builtin_amdgcn_readfirstlane(col[j + 1]);
            int s2 = __builtin_amdgcn_readfirstlane(col[j + 2]);
            int s3 = __builtin_amdgcn_readfirstlane(col[j + 3]);
            uint32_t u0 = qv[(size_t)s0 * 64 + lane];
            uint32_t u1 = qv[(size_t)s1 * 64 + lane];
            uint32_t u2 = qv[(size_t)s2 * 64 + lane];
            uint32_t u3 = qv[(size_t)s3 * 64 + lane];
            acc += gate_term(kd, u0);
            acc += gate_term(kd, u1);
            acc += gate_term(kd, u2);
            acc += gate_term(kd, u3);
            j += 4;
        }
        while (j < je) {
            int s0 = __builtin_amdgcn_readfirstlane(col[j]);
            uint32_t u0 = qv[(size_t)s0 * 64 + lane];
            acc += gate_term(kd, u0);
            ++j;
        }
        h[o] = acc + hold;
    }
}

// score[r] = sum_j hfw[r][j]*Wsc[j] + hbw[r][j]*Wsc[64+j] + bsc
__global__ __launch_bounds__(256) void score_kernel(
    const float* __restrict__ hfw, const float* __restrict__ hbw,
    const float* __restrict__ Wsc, const float* __restrict__ bsc,
    float* __restrict__ out, int N)
{
    int lane = threadIdx.x & 63;
    int wid = (blockIdx.x * 256 + threadIdx.x) >> 6;
    int nw = (gridDim.x * 256) >> 6;
    float wf = Wsc[lane], wb = Wsc[64 + lane], b = bsc[0];
    for (int r = wid; r < N; r += nw) {
        float p = hfw[(size_t)r * 64 + lane] * wf + hbw[(size_t)r * 64 + lane] * wb;
        #pragma unroll
        for (int off = 32; off; off >>= 1) p += __shfl_xor(p, off, 64);
        if (lane == 0) out[r] = p + b;
    }
}

extern "C" void kernel_launch(void* const* d_in, const int* in_sizes, int n_in,
                              void* d_out, int out_size, void* d_ws, size_t ws_size,
                              hipStream_t stream)
{
    const float* x   = (const float*)d_in[0];
    const int*   ei  = (const int*)d_in[1];
    const float* W1  = (const float*)d_in[2];
    const float* b1  = (const float*)d_in[3];
    const float* W2  = (const float*)d_in[4];
    const float* b2  = (const float*)d_in[5];
    const float* gWk = (const float*)d_in[6];
    const float* gbk = (const float*)d_in[7];
    const float* gWq = (const float*)d_in[8];
    const float* gbq = (const float*)d_in[9];
    const float* gWv = (const float*)d_in[10];
    const float* gbv = (const float*)d_in[11];
    const float* gWs = (const float*)d_in[12];
    const float* gb  = (const float*)d_in[13];
    const float* Wsc = (const float*)d_in[14];
    const float* bsc = (const float*)d_in[15];

    const int N = in_sizes[0] / HDIM;
    const int E = in_sizes[1] / 2;
    const int L = 4;

    // ---- workspace layout (floats) ----
    size_t N64 = (size_t)N * HDIM;
    size_t Npad = (size_t)N + 64;
    float* ws    = (float*)d_ws;
    float* h_fw  = ws;
    float* h_bw  = ws + N64;
    unsigned short* kbuf = (unsigned short*)(ws + 2 * N64);   // N64 ushorts
    uint32_t* qvbuf = (uint32_t*)(ws + 3 * N64);
    int* ptr_fw  = (int*)(ws + 4 * N64);
    int* ptr_bw  = ptr_fw + Npad;
    int* cnt_fw  = ptr_bw + Npad;    // reused as scatter cursor
    int* cnt_bw  = cnt_fw + Npad;
    int* col_fw  = cnt_bw + Npad;
    int* col_bw  = col_fw + E;
    int* bs_fw   = col_bw + E;
    int* bs_bw   = bs_fw + 512;

    const int* srcA = ei;        // edge_index[0]
    const int* dstA = ei + E;    // edge_index[1]

    int nb  = (N + 255) / 256;
    int ne4 = (E + 1023) / 1024;   // 4 edges per thread

    // ---- MLP (independent of CSR build) ----
    mlp_kernel<<<1024, 256, 0, stream>>>(x, W1, b1, W2, b2, h_fw, h_bw, N);

    // ---- CSR build for both directions ----
    hipMemsetAsync(cnt_fw, 0, 2 * Npad * sizeof(int), stream);
    hist_kernel<<<ne4, 256, 0, stream>>>(srcA, dstA, cnt_fw, cnt_bw, E);
    scan_local_kernel<<<dim3(nb, 2), 256, 0, stream>>>(cnt_fw, ptr_fw, bs_fw,
                                                       cnt_bw, ptr_bw, bs_bw, N);
    scan_bsum_kernel<<<2, 512, 0, stream>>>(bs_fw, bs_bw, nb);
    add_off_kernel<<<dim3(nb, 2), 256, 0, stream>>>(ptr_fw, bs_fw, cnt_fw,
                                                    ptr_bw, bs_bw, cnt_bw, N, E);
    scatter_kernel<<<ne4, 256, 0, stream>>>(srcA, dstA, cnt_fw, cnt_bw, col_fw, col_bw, E);

    int ntiles = (N + 31) / 32;
    for (int dir = 0; dir < 2; dir++) {
        float* h = dir ? h_bw : h_fw;
        const int* ptr = dir ? ptr_bw : ptr_fw;
        const int* col = dir ? col_bw : col_fw;
        for (int l = 0; l < L; l++) {
            int off = dir * L + l;
            kqvs_kernel<<<512, 256, 0, stream>>>(h,
                gWk + (size_t)off * 4096, gbk + (size_t)off * 64,
                gWq + (size_t)off * 4096, gbq + (size_t)off * 64,
                gWv + (size_t)off * 4096, gbv + (size_t)off * 64,
                gWs + (size_t)off * 4096, gb  + (size_t)off * 64,
                kbuf, qvbuf, h, N, ntiles);
            edge_csr_kernel<<<2048, 256, 0, stream>>>(ptr, col, kbuf, qvbuf, h, N);
        }
    }

    score_kernel<<<1024, 256, 0, stream>>>(h_fw, h_bw, Wsc, bsc, (float*)d_out, N);
}

// Round 5
// 1200.721 us; speedup vs baseline: 2.3919x; 1.1002x over previous
//
#include <hip/hip_runtime.h>
#include <hip/hip_bf16.h>
#include <hip/hip_fp16.h>

// N=100000 nodes, E=1200000 edges, H=64, L=4, 2 directions.
// Pipeline: mlp -> CSR build (both dirs) -> per (dir, layer): [kqvs fused matmuls]
//           -> [CSR edge gather/gate/segment-sum, 2-node/wave pipelined] -> score.

constexpr int HDIM = 64;

union H2U { uint32_t u; __half2 h2; };
union H1U { unsigned short u; __half h; };

// ---------------- MLP: h = relu(x@W1+b1)@W2+b2 ----------------
// Persistent blocks; W1,W2 in LDS; per 32-row tile: stage x transposed, FMA stage 1,
// LDS-transpose the relu intermediate, FMA stage 2. No cross-lane shuffles.
__global__ __launch_bounds__(256) void mlp_kernel(
    const float* __restrict__ x, const float* __restrict__ W1, const float* __restrict__ b1,
    const float* __restrict__ W2, const float* __restrict__ b2,
    float* __restrict__ hfw, float* __restrict__ hbw, int N, int ntiles)
{
    __shared__ float sW1[64 * 64];
    __shared__ float sW2[64 * 64];
    __shared__ float sb1[64], sb2[64];
    __shared__ float sh[64][36];
    int t = threadIdx.x;
    for (int i = t; i < 1024; i += 256) {
        ((float4*)sW1)[i] = ((const float4*)W1)[i];
        ((float4*)sW2)[i] = ((const float4*)W2)[i];
    }
    if (t < 64) { sb1[t] = b1[t]; sb2[t] = b2[t]; }
    int c = t & 63, rg = t >> 6;   // column, row-group (8 rows each)

    for (int tile = blockIdx.x; tile < ntiles; tile += gridDim.x) {
        int base = tile * 32;
        __syncthreads();   // sh free (prev stage-2 reads done); weights visible on iter 0
        for (int i = t; i < 32 * 16; i += 256) {
            int r = i >> 4, fq = i & 15;
            int row = base + r;
            float4 hv = make_float4(0.f, 0.f, 0.f, 0.f);
            if (row < N) hv = ((const float4*)x)[(size_t)row * 16 + fq];
            sh[fq * 4 + 0][r] = hv.x; sh[fq * 4 + 1][r] = hv.y;
            sh[fq * 4 + 2][r] = hv.z; sh[fq * 4 + 3][r] = hv.w;
        }
        __syncthreads();

        float acc[8];
        #pragma unroll
        for (int r = 0; r < 8; r++) acc[r] = sb1[c];
        #pragma unroll 4
        for (int f = 0; f < 64; f++) {
            float w = sW1[f * 64 + c];
            float4 ha = *(const float4*)&sh[f][rg * 8];
            float4 hb = *(const float4*)&sh[f][rg * 8 + 4];
            float hr[8] = {ha.x, ha.y, ha.z, ha.w, hb.x, hb.y, hb.z, hb.w};
            #pragma unroll
            for (int r = 0; r < 8; r++) acc[r] = fmaf(hr[r], w, acc[r]);
        }
        __syncthreads();   // all stage-1 reads of sh done
        #pragma unroll
        for (int r = 0; r < 8; r++) sh[c][rg * 8 + r] = fmaxf(acc[r], 0.f);
        __syncthreads();

        float acc2[8];
        #pragma unroll
        for (int r = 0; r < 8; r++) acc2[r] = sb2[c];
        #pragma unroll 4
        for (int f = 0; f < 64; f++) {
            float w = sW2[f * 64 + c];
            float4 ha = *(const float4*)&sh[f][rg * 8];
            float4 hb = *(const float4*)&sh[f][rg * 8 + 4];
            float hr[8] = {ha.x, ha.y, ha.z, ha.w, hb.x, hb.y, hb.z, hb.w};
            #pragma unroll
            for (int r = 0; r < 8; r++) acc2[r] = fmaf(hr[r], w, acc2[r]);
        }
        #pragma unroll
        for (int r = 0; r < 8; r++) {
            int row = base + rg * 8 + r;
            if (row < N) {
                hfw[(size_t)row * 64 + c] = acc2[r];
                hbw[(size_t)row * 64 + c] = acc2[r];
            }
        }
    }
}

// ---------------- CSR build ----------------
__global__ __launch_bounds__(256) void hist_kernel(
    const int* __restrict__ srcA, const int* __restrict__ dstA,
    int* __restrict__ cnt_fw, int* __restrict__ cnt_bw, int E)
{
    int tid = blockIdx.x * 256 + threadIdx.x;
    int S = gridDim.x * 256;
    #pragma unroll
    for (int k = 0; k < 4; k++) {
        int e = tid + k * S;
        if (e < E) {
            atomicAdd(&cnt_fw[dstA[e]], 1);
            atomicAdd(&cnt_bw[srcA[e]], 1);
        }
    }
}

// Per-block inclusive scan of 256 counts -> exclusive local, block total to bsum.
// grid.y = direction (0: fw arrays, 1: bw arrays).
__global__ __launch_bounds__(256) void scan_local_kernel(
    const int* __restrict__ c0, int* __restrict__ p0, int* __restrict__ b0,
    const int* __restrict__ c1, int* __restrict__ p1, int* __restrict__ b1, int N)
{
    const int* cnt = blockIdx.y ? c1 : c0;
    int* ptr  = blockIdx.y ? p1 : p0;
    int* bsum = blockIdx.y ? b1 : b0;
    __shared__ int sd[256];
    int t = threadIdx.x;
    int i = blockIdx.x * 256 + t;
    int val = (i < N) ? cnt[i] : 0;
    sd[t] = val;
    __syncthreads();
    #pragma unroll
    for (int off = 1; off < 256; off <<= 1) {
        int tmp = (t >= off) ? sd[t - off] : 0;
        __syncthreads();
        sd[t] += tmp;
        __syncthreads();
    }
    if (i < N) ptr[i] = sd[t] - val;       // exclusive, local
    if (t == 255) bsum[blockIdx.x] = sd[255];
}

// One block per direction (blockIdx.x in {0,1}).
__global__ __launch_bounds__(512) void scan_bsum_kernel(
    int* __restrict__ b0, int* __restrict__ b1, int nb)
{
    int* bsum = blockIdx.x ? b1 : b0;
    __shared__ int sd[512];
    int t = threadIdx.x;
    int val = (t < nb) ? bsum[t] : 0;
    sd[t] = val;
    __syncthreads();
    #pragma unroll
    for (int off = 1; off < 512; off <<= 1) {
        int tmp = (t >= off) ? sd[t - off] : 0;
        __syncthreads();
        sd[t] += tmp;
        __syncthreads();
    }
    if (t < nb) bsum[t] = sd[t] - val;     // exclusive
}

// grid.y = direction.
__global__ __launch_bounds__(256) void add_off_kernel(
    int* __restrict__ p0, const int* __restrict__ b0, int* __restrict__ u0,
    int* __restrict__ p1, const int* __restrict__ b1, int* __restrict__ u1, int N, int E)
{
    int* ptr = blockIdx.y ? p1 : p0;
    const int* bsum = blockIdx.y ? b1 : b0;
    int* cur = blockIdx.y ? u1 : u0;
    int i = blockIdx.x * 256 + threadIdx.x;
    if (i < N) {
        int p = ptr[i] + bsum[blockIdx.x];
        ptr[i] = p;
        cur[i] = p;
    }
    if (i == 0) ptr[N] = E;
}

// 4 edges per thread; all 8 returning atomics issued before any col write.
__global__ __launch_bounds__(256) void scatter_kernel(
    const int* __restrict__ srcA, const int* __restrict__ dstA,
    int* __restrict__ cur_fw, int* __restrict__ cur_bw,
    int* __restrict__ col_fw, int* __restrict__ col_bw, int E)
{
    int tid = blockIdx.x * 256 + threadIdx.x;
    int S = gridDim.x * 256;
    int s[4], d[4], pf[4], pb[4];
    bool va[4];
    #pragma unroll
    for (int k = 0; k < 4; k++) {
        int e = tid + k * S;
        va[k] = e < E;
        s[k] = va[k] ? srcA[e] : 0;
        d[k] = va[k] ? dstA[e] : 0;
    }
    #pragma unroll
    for (int k = 0; k < 4; k++) if (va[k]) pf[k] = atomicAdd(&cur_fw[d[k]], 1);
    #pragma unroll
    for (int k = 0; k < 4; k++) if (va[k]) pb[k] = atomicAdd(&cur_bw[s[k]], 1);
    #pragma unroll
    for (int k = 0; k < 4; k++) if (va[k]) { col_fw[pf[k]] = s[k]; col_bw[pb[k]] = d[k]; }
}

// ---------------- fused k/q/v/s matmuls ----------------
// Persistent blocks (512 = 2/CU): weights staged in LDS once per block, then
// grid-stride over 32-row tiles. k = fp16(h@Wk+bk), qv = pack_half2(q, v),
// h <- h@Ws+bs in place (tile staged to LDS before its rows are overwritten).
__global__ __launch_bounds__(256) void kqvs_kernel(
    const float* h,  // NOT restrict: aliases oo
    const float* __restrict__ Wk, const float* __restrict__ bk,
    const float* __restrict__ Wq, const float* __restrict__ bq,
    const float* __restrict__ Wv, const float* __restrict__ bv,
    const float* __restrict__ Ws, const float* __restrict__ bs,
    unsigned short* __restrict__ ko, uint32_t* __restrict__ qvo,
    float* oo, int N, int ntiles)
{
    __shared__ float sW[4][64 * 64];   // 64 KB
    __shared__ float sb[4][64];
    __shared__ float sh[64][36];       // transposed h tile; stride 36 floats
    int t = threadIdx.x;
    {
        const float* Wsrc[4] = {Wk, Wq, Wv, Ws};
        #pragma unroll
        for (int m = 0; m < 4; m++)
            for (int i = t; i < 1024; i += 256)
                ((float4*)sW[m])[i] = ((const float4*)Wsrc[m])[i];
        if (t < 64) { sb[0][t] = bk[t]; sb[1][t] = bq[t]; sb[2][t] = bv[t]; sb[3][t] = bs[t]; }
    }
    int c = t & 63, rg = t >> 6;  // rg in 0..3, 8 rows per thread

    for (int tile = blockIdx.x; tile < ntiles; tile += gridDim.x) {
        int base = tile * 32;
        __syncthreads();   // sh safe to overwrite (and weights visible on iter 0)
        for (int i = t; i < 32 * 16; i += 256) {   // 512 float4 loads
            int r = i >> 4, fq = i & 15;
            int row = base + r;
            float4 hv = make_float4(0.f, 0.f, 0.f, 0.f);
            if (row < N) hv = ((const float4*)h)[(size_t)row * 16 + fq];
            sh[fq * 4 + 0][r] = hv.x; sh[fq * 4 + 1][r] = hv.y;
            sh[fq * 4 + 2][r] = hv.z; sh[fq * 4 + 3][r] = hv.w;
        }
        __syncthreads();

        float acc[8][4];
        #pragma unroll
        for (int r = 0; r < 8; r++) {
            acc[r][0] = sb[0][c]; acc[r][1] = sb[1][c]; acc[r][2] = sb[2][c]; acc[r][3] = sb[3][c];
        }
        #pragma unroll 4
        for (int f = 0; f < 64; f++) {
            float w0 = sW[0][f * 64 + c], w1 = sW[1][f * 64 + c];
            float w2 = sW[2][f * 64 + c], w3 = sW[3][f * 64 + c];
            float4 ha = *(const float4*)&sh[f][rg * 8];      // broadcast b128 reads
            float4 hb = *(const float4*)&sh[f][rg * 8 + 4];
            float hr[8] = {ha.x, ha.y, ha.z, ha.w, hb.x, hb.y, hb.z, hb.w};
            #pragma unroll
            for (int r = 0; r < 8; r++) {
                acc[r][0] = fmaf(hr[r], w0, acc[r][0]);
                acc[r][1] = fmaf(hr[r], w1, acc[r][1]);
                acc[r][2] = fmaf(hr[r], w2, acc[r][2]);
                acc[r][3] = fmaf(hr[r], w3, acc[r][3]);
            }
        }
        #pragma unroll
        for (int r = 0; r < 8; r++) {
            int row = base + rg * 8 + r;
            if (row < N) {
                size_t o = (size_t)row * 64 + c;
                H1U pk1; pk1.h = __float2half_rn(acc[r][0]);
                ko[o] = pk1.u;
                H2U pk;
                pk.h2.x = __float2half_rn(acc[r][1]);
                pk.h2.y = __float2half_rn(acc[r][2]);
                qvo[o] = pk.u;
                oo[o] = acc[r][3];
            }
        }
    }
}

// ---------------- CSR edge aggregation ----------------
__device__ __forceinline__ float gate_term(float kd, uint32_t u) {
    H2U c; c.u = u;
    float qf = __low2float(c.h2);
    float vf = __high2float(c.h2);
    float eta = __builtin_amdgcn_rcpf(1.f + __expf(-(kd + qf)));
    return eta * vf;
}

// Two nodes per wave: each 32-lane half owns one node's full 64-feature row
// (2 features/lane as uint2). One gather instruction serves 2 edges; 4-deep
// unroll keeps 8 x 8B gathers in flight per wave. No cross-lane reduction.
__global__ __launch_bounds__(256) void edge_csr_kernel(
    const int* __restrict__ ptr, const int* __restrict__ col,
    const unsigned short* __restrict__ kh, const uint2* __restrict__ qv2,
    float* h, int N)
{
    int t = threadIdx.x;
    int l = t & 31;               // lane within half-wave
    int half = (t >> 5) & 1;      // which node of the pair
    int w = (blockIdx.x * 256 + t) >> 6;
    int nw = (gridDim.x * 256) >> 6;
    for (int p = w; p * 2 < N; p += nw) {
        int i = p * 2 + half;
        bool act = i < N;
        int j = 0, je = 0;
        if (act) { j = ptr[i]; je = ptr[i + 1]; }
        size_t o = (size_t)i * 64 + 2 * l;
        float kd0 = 0.f, kd1 = 0.f;
        float2 hold = make_float2(0.f, 0.f);
        if (act) {
            H2U ku; ku.u = *(const uint32_t*)(kh + o);    // two fp16 k values
            kd0 = __low2float(ku.h2); kd1 = __high2float(ku.h2);
            hold = *(const float2*)(h + o);
        }
        float a0 = 0.f, a1 = 0.f;
        while (j + 4 <= je) {
            int s0 = col[j + 0], s1 = col[j + 1], s2 = col[j + 2], s3 = col[j + 3];
            uint2 u0 = qv2[(size_t)s0 * 32 + l];
            uint2 u1 = qv2[(size_t)s1 * 32 + l];
            uint2 u2 = qv2[(size_t)s2 * 32 + l];
            uint2 u3 = qv2[(size_t)s3 * 32 + l];
            a0 += gate_term(kd0, u0.x); a1 += gate_term(kd1, u0.y);
            a0 += gate_term(kd0, u1.x); a1 += gate_term(kd1, u1.y);
            a0 += gate_term(kd0, u2.x); a1 += gate_term(kd1, u2.y);
            a0 += gate_term(kd0, u3.x); a1 += gate_term(kd1, u3.y);
            j += 4;
        }
        while (j < je) {
            int s0 = col[j];
            uint2 u0 = qv2[(size_t)s0 * 32 + l];
            a0 += gate_term(kd0, u0.x); a1 += gate_term(kd1, u0.y);
            ++j;
        }
        if (act) *(float2*)(h + o) = make_float2(a0 + hold.x, a1 + hold.y);
    }
}

// score[r] = sum_j hfw[r][j]*Wsc[j] + hbw[r][j]*Wsc[64+j] + bsc
__global__ __launch_bounds__(256) void score_kernel(
    const float* __restrict__ hfw, const float* __restrict__ hbw,
    const float* __restrict__ Wsc, const float* __restrict__ bsc,
    float* __restrict__ out, int N)
{
    int lane = threadIdx.x & 63;
    int wid = (blockIdx.x * 256 + threadIdx.x) >> 6;
    int nw = (gridDim.x * 256) >> 6;
    float wf = Wsc[lane], wb = Wsc[64 + lane], b = bsc[0];
    for (int r = wid; r < N; r += nw) {
        float p = hfw[(size_t)r * 64 + lane] * wf + hbw[(size_t)r * 64 + lane] * wb;
        #pragma unroll
        for (int off = 32; off; off >>= 1) p += __shfl_xor(p, off, 64);
        if (lane == 0) out[r] = p + b;
    }
}

extern "C" void kernel_launch(void* const* d_in, const int* in_sizes, int n_in,
                              void* d_out, int out_size, void* d_ws, size_t ws_size,
                              hipStream_t stream)
{
    const float* x   = (const float*)d_in[0];
    const int*   ei  = (const int*)d_in[1];
    const float* W1  = (const float*)d_in[2];
    const float* b1  = (const float*)d_in[3];
    const float* W2  = (const float*)d_in[4];
    const float* b2  = (const float*)d_in[5];
    const float* gWk = (const float*)d_in[6];
    const float* gbk = (const float*)d_in[7];
    const float* gWq = (const float*)d_in[8];
    const float* gbq = (const float*)d_in[9];
    const float* gWv = (const float*)d_in[10];
    const float* gbv = (const float*)d_in[11];
    const float* gWs = (const float*)d_in[12];
    const float* gb  = (const float*)d_in[13];
    const float* Wsc = (const float*)d_in[14];
    const float* bsc = (const float*)d_in[15];

    const int N = in_sizes[0] / HDIM;
    const int E = in_sizes[1] / 2;
    const int L = 4;

    // ---- workspace layout (floats) ----
    size_t N64 = (size_t)N * HDIM;
    size_t Npad = (size_t)N + 64;
    float* ws    = (float*)d_ws;
    float* h_fw  = ws;
    float* h_bw  = ws + N64;
    unsigned short* kbuf = (unsigned short*)(ws + 2 * N64);   // N64 ushorts
    uint32_t* qvbuf = (uint32_t*)(ws + 3 * N64);
    int* ptr_fw  = (int*)(ws + 4 * N64);
    int* ptr_bw  = ptr_fw + Npad;
    int* cnt_fw  = ptr_bw + Npad;    // reused as scatter cursor
    int* cnt_bw  = cnt_fw + Npad;
    int* col_fw  = cnt_bw + Npad;
    int* col_bw  = col_fw + E;
    int* bs_fw   = col_bw + E;
    int* bs_bw   = bs_fw + 512;

    const int* srcA = ei;        // edge_index[0]
    const int* dstA = ei + E;    // edge_index[1]

    int nb  = (N + 255) / 256;
    int ne4 = (E + 1023) / 1024;   // 4 edges per thread
    int ntiles = (N + 31) / 32;

    // ---- MLP (independent of CSR build) ----
    mlp_kernel<<<768, 256, 0, stream>>>(x, W1, b1, W2, b2, h_fw, h_bw, N, ntiles);

    // ---- CSR build for both directions ----
    hipMemsetAsync(cnt_fw, 0, 2 * Npad * sizeof(int), stream);
    hist_kernel<<<ne4, 256, 0, stream>>>(srcA, dstA, cnt_fw, cnt_bw, E);
    scan_local_kernel<<<dim3(nb, 2), 256, 0, stream>>>(cnt_fw, ptr_fw, bs_fw,
                                                       cnt_bw, ptr_bw, bs_bw, N);
    scan_bsum_kernel<<<2, 512, 0, stream>>>(bs_fw, bs_bw, nb);
    add_off_kernel<<<dim3(nb, 2), 256, 0, stream>>>(ptr_fw, bs_fw, cnt_fw,
                                                    ptr_bw, bs_bw, cnt_bw, N, E);
    scatter_kernel<<<ne4, 256, 0, stream>>>(srcA, dstA, cnt_fw, cnt_bw, col_fw, col_bw, E);

    for (int dir = 0; dir < 2; dir++) {
        float* h = dir ? h_bw : h_fw;
        const int* ptr = dir ? ptr_bw : ptr_fw;
        const int* col = dir ? col_bw : col_fw;
        for (int l = 0; l < L; l++) {
            int off = dir * L + l;
            kqvs_kernel<<<512, 256, 0, stream>>>(h,
                gWk + (size_t)off * 4096, gbk + (size_t)off * 64,
                gWq + (size_t)off * 4096, gbq + (size_t)off * 64,
                gWv + (size_t)off * 4096, gbv + (size_t)off * 64,
                gWs + (size_t)off * 4096, gb  + (size_t)off * 64,
                kbuf, qvbuf, h, N, ntiles);
            edge_csr_kernel<<<2048, 256, 0, stream>>>(ptr, col, kbuf, (const uint2*)qvbuf, h, N);
        }
    }

    score_kernel<<<1024, 256, 0, stream>>>(h_fw, h_bw, Wsc, bsc, (float*)d_out, N);
}

// Round 6
// 1163.808 us; speedup vs baseline: 2.4678x; 1.0317x over previous
//
#include <hip/hip_runtime.h>
#include <hip/hip_bf16.h>
#include <hip/hip_fp16.h>

// N=100000 nodes, E=1200000 edges, H=64, L=4, 2 directions.
// Pipeline: mlp -> XCD-sliced CSR build (both dirs) -> per (dir, layer):
//           [kqvs fused matmuls] -> [CSR edge gather/gate/segment-sum] -> score.

constexpr int HDIM = 64;
constexpr int NSLICE = 8;   // = #XCDs; blockIdx%8 ~ XCD id (round-robin dispatch)

union H2U { uint32_t u; __half2 h2; };
union H1U { unsigned short u; __half h; };

// ---------------- MLP: h = relu(x@W1+b1)@W2+b2 ----------------
__global__ __launch_bounds__(256) void mlp_kernel(
    const float* __restrict__ x, const float* __restrict__ W1, const float* __restrict__ b1,
    const float* __restrict__ W2, const float* __restrict__ b2,
    float* __restrict__ hfw, float* __restrict__ hbw, int N, int ntiles)
{
    __shared__ float sW1[64 * 64];
    __shared__ float sW2[64 * 64];
    __shared__ float sb1[64], sb2[64];
    __shared__ float sh[64][36];
    int t = threadIdx.x;
    for (int i = t; i < 1024; i += 256) {
        ((float4*)sW1)[i] = ((const float4*)W1)[i];
        ((float4*)sW2)[i] = ((const float4*)W2)[i];
    }
    if (t < 64) { sb1[t] = b1[t]; sb2[t] = b2[t]; }
    int c = t & 63, rg = t >> 6;   // column, row-group (8 rows each)

    for (int tile = blockIdx.x; tile < ntiles; tile += gridDim.x) {
        int base = tile * 32;
        __syncthreads();   // sh free (prev stage-2 reads done); weights visible on iter 0
        for (int i = t; i < 32 * 16; i += 256) {
            int r = i >> 4, fq = i & 15;
            int row = base + r;
            float4 hv = make_float4(0.f, 0.f, 0.f, 0.f);
            if (row < N) hv = ((const float4*)x)[(size_t)row * 16 + fq];
            sh[fq * 4 + 0][r] = hv.x; sh[fq * 4 + 1][r] = hv.y;
            sh[fq * 4 + 2][r] = hv.z; sh[fq * 4 + 3][r] = hv.w;
        }
        __syncthreads();

        float acc[8];
        #pragma unroll
        for (int r = 0; r < 8; r++) acc[r] = sb1[c];
        #pragma unroll 4
        for (int f = 0; f < 64; f++) {
            float w = sW1[f * 64 + c];
            float4 ha = *(const float4*)&sh[f][rg * 8];
            float4 hb = *(const float4*)&sh[f][rg * 8 + 4];
            float hr[8] = {ha.x, ha.y, ha.z, ha.w, hb.x, hb.y, hb.z, hb.w};
            #pragma unroll
            for (int r = 0; r < 8; r++) acc[r] = fmaf(hr[r], w, acc[r]);
        }
        __syncthreads();   // all stage-1 reads of sh done
        #pragma unroll
        for (int r = 0; r < 8; r++) sh[c][rg * 8 + r] = fmaxf(acc[r], 0.f);
        __syncthreads();

        float acc2[8];
        #pragma unroll
        for (int r = 0; r < 8; r++) acc2[r] = sb2[c];
        #pragma unroll 4
        for (int f = 0; f < 64; f++) {
            float w = sW2[f * 64 + c];
            float4 ha = *(const float4*)&sh[f][rg * 8];
            float4 hb = *(const float4*)&sh[f][rg * 8 + 4];
            float hr[8] = {ha.x, ha.y, ha.z, ha.w, hb.x, hb.y, hb.z, hb.w};
            #pragma unroll
            for (int r = 0; r < 8; r++) acc2[r] = fmaf(hr[r], w, acc2[r]);
        }
        #pragma unroll
        for (int r = 0; r < 8; r++) {
            int row = base + rg * 8 + r;
            if (row < N) {
                hfw[(size_t)row * 64 + c] = acc2[r];
                hbw[(size_t)row * 64 + c] = acc2[r];
            }
        }
    }
}

// ---------------- CSR build (XCD-sliced) ----------------
// Block b owns node-range slice (b % 8); blockIdx%8 maps ~1:1 to XCDs, so each
// slice's random writes/atomics stay in one XCD's L2 -> full-line writebacks
// happen once instead of per-XCD partial-line thrash.
__global__ __launch_bounds__(256) void hist_kernel(
    const int* __restrict__ srcA, const int* __restrict__ dstA,
    int* __restrict__ cnt_fw, int* __restrict__ cnt_bw, int E, int NS)
{
    int slice = blockIdx.x & (NSLICE - 1);
    int grank = blockIdx.x >> 3;
    int gb = gridDim.x >> 3;
    int lo = slice * NS, hi = lo + NS;
    int stride = gb * 256;
    for (int e = grank * 256 + threadIdx.x; e < E; e += stride) {
        int s = srcA[e], d = dstA[e];
        if (d >= lo && d < hi) atomicAdd(&cnt_fw[d], 1);
        if (s >= lo && s < hi) atomicAdd(&cnt_bw[s], 1);
    }
}

// Per-block inclusive scan of 256 counts -> exclusive local, block total to bsum.
// grid.y = direction (0: fw arrays, 1: bw arrays).
__global__ __launch_bounds__(256) void scan_local_kernel(
    const int* __restrict__ c0, int* __restrict__ p0, int* __restrict__ b0,
    const int* __restrict__ c1, int* __restrict__ p1, int* __restrict__ b1, int N)
{
    const int* cnt = blockIdx.y ? c1 : c0;
    int* ptr  = blockIdx.y ? p1 : p0;
    int* bsum = blockIdx.y ? b1 : b0;
    __shared__ int sd[256];
    int t = threadIdx.x;
    int i = blockIdx.x * 256 + t;
    int val = (i < N) ? cnt[i] : 0;
    sd[t] = val;
    __syncthreads();
    #pragma unroll
    for (int off = 1; off < 256; off <<= 1) {
        int tmp = (t >= off) ? sd[t - off] : 0;
        __syncthreads();
        sd[t] += tmp;
        __syncthreads();
    }
    if (i < N) ptr[i] = sd[t] - val;       // exclusive, local
    if (t == 255) bsum[blockIdx.x] = sd[255];
}

// One block per direction (blockIdx.x in {0,1}).
__global__ __launch_bounds__(512) void scan_bsum_kernel(
    int* __restrict__ b0, int* __restrict__ b1, int nb)
{
    int* bsum = blockIdx.x ? b1 : b0;
    __shared__ int sd[512];
    int t = threadIdx.x;
    int val = (t < nb) ? bsum[t] : 0;
    sd[t] = val;
    __syncthreads();
    #pragma unroll
    for (int off = 1; off < 512; off <<= 1) {
        int tmp = (t >= off) ? sd[t - off] : 0;
        __syncthreads();
        sd[t] += tmp;
        __syncthreads();
    }
    if (t < nb) bsum[t] = sd[t] - val;     // exclusive
}

// grid.y = direction.
__global__ __launch_bounds__(256) void add_off_kernel(
    int* __restrict__ p0, const int* __restrict__ b0, int* __restrict__ u0,
    int* __restrict__ p1, const int* __restrict__ b1, int* __restrict__ u1, int N, int E)
{
    int* ptr = blockIdx.y ? p1 : p0;
    const int* bsum = blockIdx.y ? b1 : b0;
    int* cur = blockIdx.y ? u1 : u0;
    int i = blockIdx.x * 256 + threadIdx.x;
    if (i < N) {
        int p = ptr[i] + bsum[blockIdx.x];
        ptr[i] = p;
        cur[i] = p;
    }
    if (i == 0) ptr[N] = E;
}

// XCD-sliced scatter: each slice group scans all edges, writes only its own
// contiguous col window (positions for a node range are contiguous in CSR).
__global__ __launch_bounds__(256) void scatter_kernel(
    const int* __restrict__ srcA, const int* __restrict__ dstA,
    int* __restrict__ cur_fw, int* __restrict__ cur_bw,
    int* __restrict__ col_fw, int* __restrict__ col_bw, int E, int NS)
{
    int slice = blockIdx.x & (NSLICE - 1);
    int grank = blockIdx.x >> 3;
    int gb = gridDim.x >> 3;
    int lo = slice * NS, hi = lo + NS;
    int stride = gb * 256;
    for (int e = grank * 256 + threadIdx.x; e < E; e += stride) {
        int s = srcA[e], d = dstA[e];
        if (d >= lo && d < hi) { int p = atomicAdd(&cur_fw[d], 1); col_fw[p] = s; }
        if (s >= lo && s < hi) { int p = atomicAdd(&cur_bw[s], 1); col_bw[p] = d; }
    }
}

// ---------------- fused k/q/v/s matmuls ----------------
// Persistent blocks (512 = 2/CU): weights staged in LDS once per block, then
// grid-stride over 32-row tiles. k = fp16(h@Wk+bk), qv = pack_half2(q, v),
// h <- h@Ws+bs in place (tile staged to LDS before its rows are overwritten).
__global__ __launch_bounds__(256) void kqvs_kernel(
    const float* h,  // NOT restrict: aliases oo
    const float* __restrict__ Wk, const float* __restrict__ bk,
    const float* __restrict__ Wq, const float* __restrict__ bq,
    const float* __restrict__ Wv, const float* __restrict__ bv,
    const float* __restrict__ Ws, const float* __restrict__ bs,
    unsigned short* __restrict__ ko, uint32_t* __restrict__ qvo,
    float* oo, int N, int ntiles)
{
    __shared__ float sW[4][64 * 64];   // 64 KB
    __shared__ float sb[4][64];
    __shared__ float sh[64][36];       // transposed h tile; stride 36 floats
    int t = threadIdx.x;
    {
        const float* Wsrc[4] = {Wk, Wq, Wv, Ws};
        #pragma unroll
        for (int m = 0; m < 4; m++)
            for (int i = t; i < 1024; i += 256)
                ((float4*)sW[m])[i] = ((const float4*)Wsrc[m])[i];
        if (t < 64) { sb[0][t] = bk[t]; sb[1][t] = bq[t]; sb[2][t] = bv[t]; sb[3][t] = bs[t]; }
    }
    int c = t & 63, rg = t >> 6;  // rg in 0..3, 8 rows per thread

    for (int tile = blockIdx.x; tile < ntiles; tile += gridDim.x) {
        int base = tile * 32;
        __syncthreads();   // sh safe to overwrite (and weights visible on iter 0)
        for (int i = t; i < 32 * 16; i += 256) {   // 512 float4 loads
            int r = i >> 4, fq = i & 15;
            int row = base + r;
            float4 hv = make_float4(0.f, 0.f, 0.f, 0.f);
            if (row < N) hv = ((const float4*)h)[(size_t)row * 16 + fq];
            sh[fq * 4 + 0][r] = hv.x; sh[fq * 4 + 1][r] = hv.y;
            sh[fq * 4 + 2][r] = hv.z; sh[fq * 4 + 3][r] = hv.w;
        }
        __syncthreads();

        float acc[8][4];
        #pragma unroll
        for (int r = 0; r < 8; r++) {
            acc[r][0] = sb[0][c]; acc[r][1] = sb[1][c]; acc[r][2] = sb[2][c]; acc[r][3] = sb[3][c];
        }
        #pragma unroll 4
        for (int f = 0; f < 64; f++) {
            float w0 = sW[0][f * 64 + c], w1 = sW[1][f * 64 + c];
            float w2 = sW[2][f * 64 + c], w3 = sW[3][f * 64 + c];
            float4 ha = *(const float4*)&sh[f][rg * 8];      // broadcast b128 reads
            float4 hb = *(const float4*)&sh[f][rg * 8 + 4];
            float hr[8] = {ha.x, ha.y, ha.z, ha.w, hb.x, hb.y, hb.z, hb.w};
            #pragma unroll
            for (int r = 0; r < 8; r++) {
                acc[r][0] = fmaf(hr[r], w0, acc[r][0]);
                acc[r][1] = fmaf(hr[r], w1, acc[r][1]);
                acc[r][2] = fmaf(hr[r], w2, acc[r][2]);
                acc[r][3] = fmaf(hr[r], w3, acc[r][3]);
            }
        }
        #pragma unroll
        for (int r = 0; r < 8; r++) {
            int row = base + rg * 8 + r;
            if (row < N) {
                size_t o = (size_t)row * 64 + c;
                H1U pk1; pk1.h = __float2half_rn(acc[r][0]);
                ko[o] = pk1.u;
                H2U pk;
                pk.h2.x = __float2half_rn(acc[r][1]);
                pk.h2.y = __float2half_rn(acc[r][2]);
                qvo[o] = pk.u;
                oo[o] = acc[r][3];
            }
        }
    }
}

// ---------------- CSR edge aggregation ----------------
__device__ __forceinline__ float gate_term(float kd, uint32_t u) {
    H2U c; c.u = u;
    float qf = __low2float(c.h2);
    float vf = __high2float(c.h2);
    float eta = __builtin_amdgcn_rcpf(1.f + __expf(-(kd + qf)));
    return eta * vf;
}

// Two nodes per wave: each 32-lane half owns one node's full 64-feature row
// (2 features/lane as uint2). 8-deep unroll keeps 8 x 8B gathers in flight.
__global__ __launch_bounds__(256) void edge_csr_kernel(
    const int* __restrict__ ptr, const int* __restrict__ col,
    const unsigned short* __restrict__ kh, const uint2* __restrict__ qv2,
    float* h, int N)
{
    int t = threadIdx.x;
    int l = t & 31;               // lane within half-wave
    int half = (t >> 5) & 1;      // which node of the pair
    int w = (blockIdx.x * 256 + t) >> 6;
    int nw = (gridDim.x * 256) >> 6;
    for (int p = w; p * 2 < N; p += nw) {
        int i = p * 2 + half;
        bool act = i < N;
        int j = 0, je = 0;
        if (act) { j = ptr[i]; je = ptr[i + 1]; }
        size_t o = (size_t)i * 64 + 2 * l;
        float kd0 = 0.f, kd1 = 0.f;
        float2 hold = make_float2(0.f, 0.f);
        if (act) {
            H2U ku; ku.u = *(const uint32_t*)(kh + o);    // two fp16 k values
            kd0 = __low2float(ku.h2); kd1 = __high2float(ku.h2);
            hold = *(const float2*)(h + o);
        }
        float a0 = 0.f, a1 = 0.f;
        while (j + 8 <= je) {
            int s0 = col[j + 0], s1 = col[j + 1], s2 = col[j + 2], s3 = col[j + 3];
            int s4 = col[j + 4], s5 = col[j + 5], s6 = col[j + 6], s7 = col[j + 7];
            uint2 u0 = qv2[(size_t)s0 * 32 + l];
            uint2 u1 = qv2[(size_t)s1 * 32 + l];
            uint2 u2 = qv2[(size_t)s2 * 32 + l];
            uint2 u3 = qv2[(size_t)s3 * 32 + l];
            uint2 u4 = qv2[(size_t)s4 * 32 + l];
            uint2 u5 = qv2[(size_t)s5 * 32 + l];
            uint2 u6 = qv2[(size_t)s6 * 32 + l];
            uint2 u7 = qv2[(size_t)s7 * 32 + l];
            a0 += gate_term(kd0, u0.x); a1 += gate_term(kd1, u0.y);
            a0 += gate_term(kd0, u1.x); a1 += gate_term(kd1, u1.y);
            a0 += gate_term(kd0, u2.x); a1 += gate_term(kd1, u2.y);
            a0 += gate_term(kd0, u3.x); a1 += gate_term(kd1, u3.y);
            a0 += gate_term(kd0, u4.x); a1 += gate_term(kd1, u4.y);
            a0 += gate_term(kd0, u5.x); a1 += gate_term(kd1, u5.y);
            a0 += gate_term(kd0, u6.x); a1 += gate_term(kd1, u6.y);
            a0 += gate_term(kd0, u7.x); a1 += gate_term(kd1, u7.y);
            j += 8;
        }
        if (j + 4 <= je) {
            int s0 = col[j + 0], s1 = col[j + 1], s2 = col[j + 2], s3 = col[j + 3];
            uint2 u0 = qv2[(size_t)s0 * 32 + l];
            uint2 u1 = qv2[(size_t)s1 * 32 + l];
            uint2 u2 = qv2[(size_t)s2 * 32 + l];
            uint2 u3 = qv2[(size_t)s3 * 32 + l];
            a0 += gate_term(kd0, u0.x); a1 += gate_term(kd1, u0.y);
            a0 += gate_term(kd0, u1.x); a1 += gate_term(kd1, u1.y);
            a0 += gate_term(kd0, u2.x); a1 += gate_term(kd1, u2.y);
            a0 += gate_term(kd0, u3.x); a1 += gate_term(kd1, u3.y);
            j += 4;
        }
        while (j < je) {
            int s0 = col[j];
            uint2 u0 = qv2[(size_t)s0 * 32 + l];
            a0 += gate_term(kd0, u0.x); a1 += gate_term(kd1, u0.y);
            ++j;
        }
        if (act) *(float2*)(h + o) = make_float2(a0 + hold.x, a1 + hold.y);
    }
}

// score[r] = sum_j hfw[r][j]*Wsc[j] + hbw[r][j]*Wsc[64+j] + bsc
__global__ __launch_bounds__(256) void score_kernel(
    const float* __restrict__ hfw, const float* __restrict__ hbw,
    const float* __restrict__ Wsc, const float* __restrict__ bsc,
    float* __restrict__ out, int N)
{
    int lane = threadIdx.x & 63;
    int wid = (blockIdx.x * 256 + threadIdx.x) >> 6;
    int nw = (gridDim.x * 256) >> 6;
    float wf = Wsc[lane], wb = Wsc[64 + lane], b = bsc[0];
    for (int r = wid; r < N; r += nw) {
        float p = hfw[(size_t)r * 64 + lane] * wf + hbw[(size_t)r * 64 + lane] * wb;
        #pragma unroll
        for (int off = 32; off; off >>= 1) p += __shfl_xor(p, off, 64);
        if (lane == 0) out[r] = p + b;
    }
}

extern "C" void kernel_launch(void* const* d_in, const int* in_sizes, int n_in,
                              void* d_out, int out_size, void* d_ws, size_t ws_size,
                              hipStream_t stream)
{
    const float* x   = (const float*)d_in[0];
    const int*   ei  = (const int*)d_in[1];
    const float* W1  = (const float*)d_in[2];
    const float* b1  = (const float*)d_in[3];
    const float* W2  = (const float*)d_in[4];
    const float* b2  = (const float*)d_in[5];
    const float* gWk = (const float*)d_in[6];
    const float* gbk = (const float*)d_in[7];
    const float* gWq = (const float*)d_in[8];
    const float* gbq = (const float*)d_in[9];
    const float* gWv = (const float*)d_in[10];
    const float* gbv = (const float*)d_in[11];
    const float* gWs = (const float*)d_in[12];
    const float* gb  = (const float*)d_in[13];
    const float* Wsc = (const float*)d_in[14];
    const float* bsc = (const float*)d_in[15];

    const int N = in_sizes[0] / HDIM;
    const int E = in_sizes[1] / 2;
    const int L = 4;
    const int NS = (N + NSLICE - 1) / NSLICE;   // nodes per slice

    // ---- workspace layout (floats) ----
    size_t N64 = (size_t)N * HDIM;
    size_t Npad = (size_t)N + 64;
    float* ws    = (float*)d_ws;
    float* h_fw  = ws;
    float* h_bw  = ws + N64;
    unsigned short* kbuf = (unsigned short*)(ws + 2 * N64);   // N64 ushorts
    uint32_t* qvbuf = (uint32_t*)(ws + 3 * N64);
    int* ptr_fw  = (int*)(ws + 4 * N64);
    int* ptr_bw  = ptr_fw + Npad;
    int* cnt_fw  = ptr_bw + Npad;    // reused as scatter cursor
    int* cnt_bw  = cnt_fw + Npad;
    int* col_fw  = cnt_bw + Npad;
    int* col_bw  = col_fw + E;
    int* bs_fw   = col_bw + E;
    int* bs_bw   = bs_fw + 512;

    const int* srcA = ei;        // edge_index[0]
    const int* dstA = ei + E;    // edge_index[1]

    int nb  = (N + 255) / 256;
    int ntiles = (N + 31) / 32;

    // ---- MLP (independent of CSR build) ----
    mlp_kernel<<<768, 256, 0, stream>>>(x, W1, b1, W2, b2, h_fw, h_bw, N, ntiles);

    // ---- CSR build for both directions (XCD-sliced) ----
    hipMemsetAsync(cnt_fw, 0, 2 * Npad * sizeof(int), stream);
    hist_kernel<<<2048, 256, 0, stream>>>(srcA, dstA, cnt_fw, cnt_bw, E, NS);
    scan_local_kernel<<<dim3(nb, 2), 256, 0, stream>>>(cnt_fw, ptr_fw, bs_fw,
                                                       cnt_bw, ptr_bw, bs_bw, N);
    scan_bsum_kernel<<<2, 512, 0, stream>>>(bs_fw, bs_bw, nb);
    add_off_kernel<<<dim3(nb, 2), 256, 0, stream>>>(ptr_fw, bs_fw, cnt_fw,
                                                    ptr_bw, bs_bw, cnt_bw, N, E);
    scatter_kernel<<<2048, 256, 0, stream>>>(srcA, dstA, cnt_fw, cnt_bw, col_fw, col_bw, E, NS);

    for (int dir = 0; dir < 2; dir++) {
        float* h = dir ? h_bw : h_fw;
        const int* ptr = dir ? ptr_bw : ptr_fw;
        const int* col = dir ? col_bw : col_fw;
        for (int l = 0; l < L; l++) {
            int off = dir * L + l;
            kqvs_kernel<<<512, 256, 0, stream>>>(h,
                gWk + (size_t)off * 4096, gbk + (size_t)off * 64,
                gWq + (size_t)off * 4096, gbq + (size_t)off * 64,
                gWv + (size_t)off * 4096, gbv + (size_t)off * 64,
                gWs + (size_t)off * 4096, gb  + (size_t)off * 64,
                kbuf, qvbuf, h, N, ntiles);
            edge_csr_kernel<<<2048, 256, 0, stream>>>(ptr, col, kbuf, (const uint2*)qvbuf, h, N);
        }
    }

    score_kernel<<<1024, 256, 0, stream>>>(h_fw, h_bw, Wsc, bsc, (float*)d_out, N);
}

// Round 7
// 1008.555 us; speedup vs baseline: 2.8477x; 1.1539x over previous
//
#include <hip/hip_runtime.h>
#include <hip/hip_bf16.h>
#include <hip/hip_fp16.h>

// N=100000 nodes, E=1200000 edges, H=64, L=4, 2 directions.
// Pipeline: mlp -> CSR build (XCD-sliced scatter) -> per (dir, layer):
//           [kqvs fused fp16-dot2 matmuls] -> [CSR edge gather/gate/sum] -> score.

constexpr int HDIM = 64;
constexpr int NSLICE = 8;   // = #XCDs; blockIdx%8 ~ XCD id (round-robin dispatch)

union H2U { uint32_t u; __half2 h2; };
union H1U { unsigned short u; __half h; };

typedef _Float16 f16x2 __attribute__((ext_vector_type(2)));
union F2U { uint32_t u; f16x2 h; };

__device__ __forceinline__ float fdot2(f16x2 a, f16x2 b, float c) {
#if __has_builtin(__builtin_amdgcn_fdot2)
    return __builtin_amdgcn_fdot2(a, b, c, false);
#else
    return fmaf((float)a.x, (float)b.x, fmaf((float)a.y, (float)b.y, c));
#endif
}

// ---------------- MLP: h = relu(x@W1+b1)@W2+b2 ----------------
__global__ __launch_bounds__(256) void mlp_kernel(
    const float* __restrict__ x, const float* __restrict__ W1, const float* __restrict__ b1,
    const float* __restrict__ W2, const float* __restrict__ b2,
    float* __restrict__ hfw, float* __restrict__ hbw, int N, int ntiles)
{
    __shared__ float sW1[64 * 64];
    __shared__ float sW2[64 * 64];
    __shared__ float sb1[64], sb2[64];
    __shared__ float sh[64][36];
    int t = threadIdx.x;
    for (int i = t; i < 1024; i += 256) {
        ((float4*)sW1)[i] = ((const float4*)W1)[i];
        ((float4*)sW2)[i] = ((const float4*)W2)[i];
    }
    if (t < 64) { sb1[t] = b1[t]; sb2[t] = b2[t]; }
    int c = t & 63, rg = t >> 6;   // column, row-group (8 rows each)

    for (int tile = blockIdx.x; tile < ntiles; tile += gridDim.x) {
        int base = tile * 32;
        __syncthreads();   // sh free (prev stage-2 reads done); weights visible on iter 0
        for (int i = t; i < 32 * 16; i += 256) {
            int r = i >> 4, fq = i & 15;
            int row = base + r;
            float4 hv = make_float4(0.f, 0.f, 0.f, 0.f);
            if (row < N) hv = ((const float4*)x)[(size_t)row * 16 + fq];
            sh[fq * 4 + 0][r] = hv.x; sh[fq * 4 + 1][r] = hv.y;
            sh[fq * 4 + 2][r] = hv.z; sh[fq * 4 + 3][r] = hv.w;
        }
        __syncthreads();

        float acc[8];
        #pragma unroll
        for (int r = 0; r < 8; r++) acc[r] = sb1[c];
        #pragma unroll 4
        for (int f = 0; f < 64; f++) {
            float w = sW1[f * 64 + c];
            float4 ha = *(const float4*)&sh[f][rg * 8];
            float4 hb = *(const float4*)&sh[f][rg * 8 + 4];
            float hr[8] = {ha.x, ha.y, ha.z, ha.w, hb.x, hb.y, hb.z, hb.w};
            #pragma unroll
            for (int r = 0; r < 8; r++) acc[r] = fmaf(hr[r], w, acc[r]);
        }
        __syncthreads();   // all stage-1 reads of sh done
        #pragma unroll
        for (int r = 0; r < 8; r++) sh[c][rg * 8 + r] = fmaxf(acc[r], 0.f);
        __syncthreads();

        float acc2[8];
        #pragma unroll
        for (int r = 0; r < 8; r++) acc2[r] = sb2[c];
        #pragma unroll 4
        for (int f = 0; f < 64; f++) {
            float w = sW2[f * 64 + c];
            float4 ha = *(const float4*)&sh[f][rg * 8];
            float4 hb = *(const float4*)&sh[f][rg * 8 + 4];
            float hr[8] = {ha.x, ha.y, ha.z, ha.w, hb.x, hb.y, hb.z, hb.w};
            #pragma unroll
            for (int r = 0; r < 8; r++) acc2[r] = fmaf(hr[r], w, acc2[r]);
        }
        #pragma unroll
        for (int r = 0; r < 8; r++) {
            int row = base + rg * 8 + r;
            if (row < N) {
                hfw[(size_t)row * 64 + c] = acc2[r];
                hbw[(size_t)row * 64 + c] = acc2[r];
            }
        }
    }
}

// ---------------- CSR build ----------------
// Unsliced hist: reads E once; cnt arrays are tiny (L2-resident atomics).
__global__ __launch_bounds__(256) void hist_kernel(
    const int* __restrict__ srcA, const int* __restrict__ dstA,
    int* __restrict__ cnt_fw, int* __restrict__ cnt_bw, int E)
{
    int tid = blockIdx.x * 256 + threadIdx.x;
    int S = gridDim.x * 256;
    #pragma unroll
    for (int k = 0; k < 4; k++) {
        int e = tid + k * S;
        if (e < E) {
            atomicAdd(&cnt_fw[dstA[e]], 1);
            atomicAdd(&cnt_bw[srcA[e]], 1);
        }
    }
}

// Per-block inclusive scan of 256 counts -> exclusive local, block total to bsum.
// grid.y = direction (0: fw arrays, 1: bw arrays).
__global__ __launch_bounds__(256) void scan_local_kernel(
    const int* __restrict__ c0, int* __restrict__ p0, int* __restrict__ b0,
    const int* __restrict__ c1, int* __restrict__ p1, int* __restrict__ b1, int N)
{
    const int* cnt = blockIdx.y ? c1 : c0;
    int* ptr  = blockIdx.y ? p1 : p0;
    int* bsum = blockIdx.y ? b1 : b0;
    __shared__ int sd[256];
    int t = threadIdx.x;
    int i = blockIdx.x * 256 + t;
    int val = (i < N) ? cnt[i] : 0;
    sd[t] = val;
    __syncthreads();
    #pragma unroll
    for (int off = 1; off < 256; off <<= 1) {
        int tmp = (t >= off) ? sd[t - off] : 0;
        __syncthreads();
        sd[t] += tmp;
        __syncthreads();
    }
    if (i < N) ptr[i] = sd[t] - val;       // exclusive, local
    if (t == 255) bsum[blockIdx.x] = sd[255];
}

// One block per direction (blockIdx.x in {0,1}).
__global__ __launch_bounds__(512) void scan_bsum_kernel(
    int* __restrict__ b0, int* __restrict__ b1, int nb)
{
    int* bsum = blockIdx.x ? b1 : b0;
    __shared__ int sd[512];
    int t = threadIdx.x;
    int val = (t < nb) ? bsum[t] : 0;
    sd[t] = val;
    __syncthreads();
    #pragma unroll
    for (int off = 1; off < 512; off <<= 1) {
        int tmp = (t >= off) ? sd[t - off] : 0;
        __syncthreads();
        sd[t] += tmp;
        __syncthreads();
    }
    if (t < nb) bsum[t] = sd[t] - val;     // exclusive
}

// grid.y = direction.
__global__ __launch_bounds__(256) void add_off_kernel(
    int* __restrict__ p0, const int* __restrict__ b0, int* __restrict__ u0,
    int* __restrict__ p1, const int* __restrict__ b1, int* __restrict__ u1, int N, int E)
{
    int* ptr = blockIdx.y ? p1 : p0;
    const int* bsum = blockIdx.y ? b1 : b0;
    int* cur = blockIdx.y ? u1 : u0;
    int i = blockIdx.x * 256 + threadIdx.x;
    if (i < N) {
        int p = ptr[i] + bsum[blockIdx.x];
        ptr[i] = p;
        cur[i] = p;
    }
    if (i == 0) ptr[N] = E;
}

// XCD-sliced scatter: each slice group scans all edges, writes only its own
// contiguous col window (positions for a node range are contiguous in CSR).
__global__ __launch_bounds__(256) void scatter_kernel(
    const int* __restrict__ srcA, const int* __restrict__ dstA,
    int* __restrict__ cur_fw, int* __restrict__ cur_bw,
    int* __restrict__ col_fw, int* __restrict__ col_bw, int E, int NS)
{
    int slice = blockIdx.x & (NSLICE - 1);
    int grank = blockIdx.x >> 3;
    int gb = gridDim.x >> 3;
    int lo = slice * NS, hi = lo + NS;
    int stride = gb * 256;
    for (int e = grank * 256 + threadIdx.x; e < E; e += stride) {
        int s = srcA[e], d = dstA[e];
        if (d >= lo && d < hi) { int p = atomicAdd(&cur_fw[d], 1); col_fw[p] = s; }
        if (s >= lo && s < hi) { int p = atomicAdd(&cur_bw[s], 1); col_bw[p] = d; }
    }
}

// ---------------- fused k/q/v/s matmuls (fp16 dot2) ----------------
// LDS: weights as paired half2 (32 KB) + h tile as half2 (4.3 KB) -> 4 blocks/CU.
// sW[m][fp*64+c] = (W[2fp][c], W[2fp+1][c]); sh[fp][r] = (h[r][2fp], h[r][2fp+1]).
// k = fp16(h@Wk+bk), qv = pack(q,v) fp16, h <- h@Ws+bs in place (fp32).
__global__ __launch_bounds__(256) void kqvs_kernel(
    const float* h,  // NOT restrict: aliases oo
    const float* __restrict__ Wk, const float* __restrict__ bk,
    const float* __restrict__ Wq, const float* __restrict__ bq,
    const float* __restrict__ Wv, const float* __restrict__ bv,
    const float* __restrict__ Ws, const float* __restrict__ bs,
    unsigned short* __restrict__ ko, uint32_t* __restrict__ qvo,
    float* oo, int N, int ntiles)
{
    __shared__ f16x2 sW[4][32 * 64];   // 4 * 8 KB = 32 KB
    __shared__ float sb[4][64];        // 1 KB
    __shared__ f16x2 sh[32][34];       // 4.25 KB; pad 34 -> 2-way max on staging
    int t = threadIdx.x;
    {
        const float* Wsrc[4] = {Wk, Wq, Wv, Ws};
        #pragma unroll
        for (int m = 0; m < 4; m++) {
            const float* W = Wsrc[m];
            for (int i = t; i < 512; i += 256) {
                int fp = i >> 4, cq = (i & 15) * 4;
                float4 wa = *(const float4*)&W[(size_t)(2 * fp) * 64 + cq];
                float4 wb = *(const float4*)&W[(size_t)(2 * fp + 1) * 64 + cq];
                f16x2 p0 = {(_Float16)wa.x, (_Float16)wb.x};
                f16x2 p1 = {(_Float16)wa.y, (_Float16)wb.y};
                f16x2 p2 = {(_Float16)wa.z, (_Float16)wb.z};
                f16x2 p3 = {(_Float16)wa.w, (_Float16)wb.w};
                sW[m][fp * 64 + cq + 0] = p0;
                sW[m][fp * 64 + cq + 1] = p1;
                sW[m][fp * 64 + cq + 2] = p2;
                sW[m][fp * 64 + cq + 3] = p3;
            }
        }
        if (t < 64) { sb[0][t] = bk[t]; sb[1][t] = bq[t]; sb[2][t] = bv[t]; sb[3][t] = bs[t]; }
    }
    int c = t & 63, rg = t >> 6;  // rg in 0..3, 8 rows per thread

    for (int tile = blockIdx.x; tile < ntiles; tile += gridDim.x) {
        int base = tile * 32;
        __syncthreads();   // sh safe to overwrite (and weights visible on iter 0)
        for (int i = t; i < 32 * 16; i += 256) {   // 512 float4 loads
            int r = i >> 4, fq = i & 15;
            int row = base + r;
            float4 hv = make_float4(0.f, 0.f, 0.f, 0.f);
            if (row < N) hv = ((const float4*)h)[(size_t)row * 16 + fq];
            f16x2 pa = {(_Float16)hv.x, (_Float16)hv.y};
            f16x2 pb = {(_Float16)hv.z, (_Float16)hv.w};
            sh[fq * 2 + 0][r] = pa;
            sh[fq * 2 + 1][r] = pb;
        }
        __syncthreads();

        float acc[8][4];
        #pragma unroll
        for (int r = 0; r < 8; r++) {
            acc[r][0] = sb[0][c]; acc[r][1] = sb[1][c]; acc[r][2] = sb[2][c]; acc[r][3] = sb[3][c];
        }
        #pragma unroll 4
        for (int fp = 0; fp < 32; fp++) {
            f16x2 w0 = sW[0][fp * 64 + c], w1 = sW[1][fp * 64 + c];
            f16x2 w2 = sW[2][fp * 64 + c], w3 = sW[3][fp * 64 + c];
            // 8 half2 (32 B) broadcast reads
            uint4 A = *(const uint4*)&sh[fp][rg * 8];
            uint4 B = *(const uint4*)&sh[fp][rg * 8 + 4];
            uint32_t hw[8] = {A.x, A.y, A.z, A.w, B.x, B.y, B.z, B.w};
            #pragma unroll
            for (int r = 0; r < 8; r++) {
                F2U hr; hr.u = hw[r];
                acc[r][0] = fdot2(hr.h, w0, acc[r][0]);
                acc[r][1] = fdot2(hr.h, w1, acc[r][1]);
                acc[r][2] = fdot2(hr.h, w2, acc[r][2]);
                acc[r][3] = fdot2(hr.h, w3, acc[r][3]);
            }
        }
        #pragma unroll
        for (int r = 0; r < 8; r++) {
            int row = base + rg * 8 + r;
            if (row < N) {
                size_t o = (size_t)row * 64 + c;
                H1U pk1; pk1.h = __float2half_rn(acc[r][0]);
                ko[o] = pk1.u;
                H2U pk;
                pk.h2.x = __float2half_rn(acc[r][1]);
                pk.h2.y = __float2half_rn(acc[r][2]);
                qvo[o] = pk.u;
                oo[o] = acc[r][3];
            }
        }
    }
}

// ---------------- CSR edge aggregation ----------------
__device__ __forceinline__ float gate_term(float kd, uint32_t u) {
    H2U c; c.u = u;
    float qf = __low2float(c.h2);
    float vf = __high2float(c.h2);
    float eta = __builtin_amdgcn_rcpf(1.f + __expf(-(kd + qf)));
    return eta * vf;
}

// Two nodes per wave: each 32-lane half owns one node's full 64-feature row
// (2 features/lane as uint2). 8-deep unroll keeps 8 x 8B gathers in flight.
__global__ __launch_bounds__(256) void edge_csr_kernel(
    const int* __restrict__ ptr, const int* __restrict__ col,
    const unsigned short* __restrict__ kh, const uint2* __restrict__ qv2,
    float* h, int N)
{
    int t = threadIdx.x;
    int l = t & 31;               // lane within half-wave
    int half = (t >> 5) & 1;      // which node of the pair
    int w = (blockIdx.x * 256 + t) >> 6;
    int nw = (gridDim.x * 256) >> 6;
    for (int p = w; p * 2 < N; p += nw) {
        int i = p * 2 + half;
        bool act = i < N;
        int j = 0, je = 0;
        if (act) { j = ptr[i]; je = ptr[i + 1]; }
        size_t o = (size_t)i * 64 + 2 * l;
        float kd0 = 0.f, kd1 = 0.f;
        float2 hold = make_float2(0.f, 0.f);
        if (act) {
            H2U ku; ku.u = *(const uint32_t*)(kh + o);    // two fp16 k values
            kd0 = __low2float(ku.h2); kd1 = __high2float(ku.h2);
            hold = *(const float2*)(h + o);
        }
        float a0 = 0.f, a1 = 0.f;
        while (j + 8 <= je) {
            int s0 = col[j + 0], s1 = col[j + 1], s2 = col[j + 2], s3 = col[j + 3];
            int s4 = col[j + 4], s5 = col[j + 5], s6 = col[j + 6], s7 = col[j + 7];
            uint2 u0 = qv2[(size_t)s0 * 32 + l];
            uint2 u1 = qv2[(size_t)s1 * 32 + l];
            uint2 u2 = qv2[(size_t)s2 * 32 + l];
            uint2 u3 = qv2[(size_t)s3 * 32 + l];
            uint2 u4 = qv2[(size_t)s4 * 32 + l];
            uint2 u5 = qv2[(size_t)s5 * 32 + l];
            uint2 u6 = qv2[(size_t)s6 * 32 + l];
            uint2 u7 = qv2[(size_t)s7 * 32 + l];
            a0 += gate_term(kd0, u0.x); a1 += gate_term(kd1, u0.y);
            a0 += gate_term(kd0, u1.x); a1 += gate_term(kd1, u1.y);
            a0 += gate_term(kd0, u2.x); a1 += gate_term(kd1, u2.y);
            a0 += gate_term(kd0, u3.x); a1 += gate_term(kd1, u3.y);
            a0 += gate_term(kd0, u4.x); a1 += gate_term(kd1, u4.y);
            a0 += gate_term(kd0, u5.x); a1 += gate_term(kd1, u5.y);
            a0 += gate_term(kd0, u6.x); a1 += gate_term(kd1, u6.y);
            a0 += gate_term(kd0, u7.x); a1 += gate_term(kd1, u7.y);
            j += 8;
        }
        if (j + 4 <= je) {
            int s0 = col[j + 0], s1 = col[j + 1], s2 = col[j + 2], s3 = col[j + 3];
            uint2 u0 = qv2[(size_t)s0 * 32 + l];
            uint2 u1 = qv2[(size_t)s1 * 32 + l];
            uint2 u2 = qv2[(size_t)s2 * 32 + l];
            uint2 u3 = qv2[(size_t)s3 * 32 + l];
            a0 += gate_term(kd0, u0.x); a1 += gate_term(kd1, u0.y);
            a0 += gate_term(kd0, u1.x); a1 += gate_term(kd1, u1.y);
            a0 += gate_term(kd0, u2.x); a1 += gate_term(kd1, u2.y);
            a0 += gate_term(kd0, u3.x); a1 += gate_term(kd1, u3.y);
            j += 4;
        }
        while (j < je) {
            int s0 = col[j];
            uint2 u0 = qv2[(size_t)s0 * 32 + l];
            a0 += gate_term(kd0, u0.x); a1 += gate_term(kd1, u0.y);
            ++j;
        }
        if (act) *(float2*)(h + o) = make_float2(a0 + hold.x, a1 + hold.y);
    }
}

// score[r] = sum_j hfw[r][j]*Wsc[j] + hbw[r][j]*Wsc[64+j] + bsc
__global__ __launch_bounds__(256) void score_kernel(
    const float* __restrict__ hfw, const float* __restrict__ hbw,
    const float* __restrict__ Wsc, const float* __restrict__ bsc,
    float* __restrict__ out, int N)
{
    int lane = threadIdx.x & 63;
    int wid = (blockIdx.x * 256 + threadIdx.x) >> 6;
    int nw = (gridDim.x * 256) >> 6;
    float wf = Wsc[lane], wb = Wsc[64 + lane], b = bsc[0];
    for (int r = wid; r < N; r += nw) {
        float p = hfw[(size_t)r * 64 + lane] * wf + hbw[(size_t)r * 64 + lane] * wb;
        #pragma unroll
        for (int off = 32; off; off >>= 1) p += __shfl_xor(p, off, 64);
        if (lane == 0) out[r] = p + b;
    }
}

extern "C" void kernel_launch(void* const* d_in, const int* in_sizes, int n_in,
                              void* d_out, int out_size, void* d_ws, size_t ws_size,
                              hipStream_t stream)
{
    const float* x   = (const float*)d_in[0];
    const int*   ei  = (const int*)d_in[1];
    const float* W1  = (const float*)d_in[2];
    const float* b1  = (const float*)d_in[3];
    const float* W2  = (const float*)d_in[4];
    const float* b2  = (const float*)d_in[5];
    const float* gWk = (const float*)d_in[6];
    const float* gbk = (const float*)d_in[7];
    const float* gWq = (const float*)d_in[8];
    const float* gbq = (const float*)d_in[9];
    const float* gWv = (const float*)d_in[10];
    const float* gbv = (const float*)d_in[11];
    const float* gWs = (const float*)d_in[12];
    const float* gb  = (const float*)d_in[13];
    const float* Wsc = (const float*)d_in[14];
    const float* bsc = (const float*)d_in[15];

    const int N = in_sizes[0] / HDIM;
    const int E = in_sizes[1] / 2;
    const int L = 4;
    const int NS = (N + NSLICE - 1) / NSLICE;   // nodes per slice

    // ---- workspace layout (floats) ----
    size_t N64 = (size_t)N * HDIM;
    size_t Npad = (size_t)N + 64;
    float* ws    = (float*)d_ws;
    float* h_fw  = ws;
    float* h_bw  = ws + N64;
    unsigned short* kbuf = (unsigned short*)(ws + 2 * N64);   // N64 ushorts
    uint32_t* qvbuf = (uint32_t*)(ws + 3 * N64);
    int* ptr_fw  = (int*)(ws + 4 * N64);
    int* ptr_bw  = ptr_fw + Npad;
    int* cnt_fw  = ptr_bw + Npad;    // reused as scatter cursor
    int* cnt_bw  = cnt_fw + Npad;
    int* col_fw  = cnt_bw + Npad;
    int* col_bw  = col_fw + E;
    int* bs_fw   = col_bw + E;
    int* bs_bw   = bs_fw + 512;

    const int* srcA = ei;        // edge_index[0]
    const int* dstA = ei + E;    // edge_index[1]

    int nb  = (N + 255) / 256;
    int ne4 = (E + 1023) / 1024;   // 4 edges per thread
    int ntiles = (N + 31) / 32;

    // ---- MLP (independent of CSR build) ----
    mlp_kernel<<<768, 256, 0, stream>>>(x, W1, b1, W2, b2, h_fw, h_bw, N, ntiles);

    // ---- CSR build for both directions ----
    hipMemsetAsync(cnt_fw, 0, 2 * Npad * sizeof(int), stream);
    hist_kernel<<<ne4, 256, 0, stream>>>(srcA, dstA, cnt_fw, cnt_bw, E);
    scan_local_kernel<<<dim3(nb, 2), 256, 0, stream>>>(cnt_fw, ptr_fw, bs_fw,
                                                       cnt_bw, ptr_bw, bs_bw, N);
    scan_bsum_kernel<<<2, 512, 0, stream>>>(bs_fw, bs_bw, nb);
    add_off_kernel<<<dim3(nb, 2), 256, 0, stream>>>(ptr_fw, bs_fw, cnt_fw,
                                                    ptr_bw, bs_bw, cnt_bw, N, E);
    scatter_kernel<<<2048, 256, 0, stream>>>(srcA, dstA, cnt_fw, cnt_bw, col_fw, col_bw, E, NS);

    for (int dir = 0; dir < 2; dir++) {
        float* h = dir ? h_bw : h_fw;
        const int* ptr = dir ? ptr_bw : ptr_fw;
        const int* col = dir ? col_bw : col_fw;
        for (int l = 0; l < L; l++) {
            int off = dir * L + l;
            kqvs_kernel<<<1024, 256, 0, stream>>>(h,
                gWk + (size_t)off * 4096, gbk + (size_t)off * 64,
                gWq + (size_t)off * 4096, gbq + (size_t)off * 64,
                gWv + (size_t)off * 4096, gbv + (size_t)off * 64,
                gWs + (size_t)off * 4096, gb  + (size_t)off * 64,
                kbuf, qvbuf, h, N, ntiles);
            edge_csr_kernel<<<2048, 256, 0, stream>>>(ptr, col, kbuf, (const uint2*)qvbuf, h, N);
        }
    }

    score_kernel<<<1024, 256, 0, stream>>>(h_fw, h_bw, Wsc, bsc, (float*)d_out, N);
}